// Round 2
// baseline (661.271 us; speedup 1.0000x reference)
//
#include <hip/hip_runtime.h>

typedef __attribute__((ext_vector_type(8))) short s16x8;
typedef __attribute__((ext_vector_type(8))) unsigned short u16x8;
typedef __attribute__((ext_vector_type(4))) unsigned short u16x4;
typedef __attribute__((ext_vector_type(4))) float f32x4;

__device__ __forceinline__ unsigned short f2bf(float f) {
  union { float f; unsigned int u; } v; v.f = f;
  unsigned int r = (v.u + 0x7FFFu + ((v.u >> 16) & 1u)) >> 16;
  return (unsigned short)r;
}
__device__ __forceinline__ float bf2f(unsigned short h) {
  union { unsigned int u; float f; } v; v.u = ((unsigned int)h) << 16;
  return v.f;
}
__device__ __forceinline__ float gelu(float x) {
  return 0.5f * x * (1.f + erff(x * 0.70710678118654752f));
}
__device__ __forceinline__ float fexp2(float x) {
  float r; asm("v_exp_f32 %0, %1" : "=v"(r) : "v"(x)); return r;
}

__device__ __forceinline__ void gld16(const void* g, void* l) {
  __builtin_amdgcn_global_load_lds(
      (const __attribute__((address_space(1))) unsigned int*)g,
      (__attribute__((address_space(3))) unsigned int*)l, 16, 0, 0);
}

__device__ __forceinline__ float blk_sum(float v, float* red, int tid, int nw) {
#pragma unroll
  for (int m = 32; m >= 1; m >>= 1) v += __shfl_xor(v, m);
  __syncthreads();
  if ((tid & 63) == 0) red[tid >> 6] = v;
  __syncthreads();
  float t = 0.f;
  for (int i = 0; i < nw; ++i) t += red[i];
  return t;
}

// ---------------- tiled transpose: fp32 [R][C] -> bf16 [C][R], batched ----------------
// grid: (C/32, R/32, batch), 256 threads
__global__ __launch_bounds__(256) void k_tr(
    const float* __restrict__ in, unsigned short* __restrict__ out,
    int inRS, int outRS, long inBS, long outBS) {
  __shared__ float t[32][33];
  const float* ip = in + (size_t)blockIdx.z * inBS;
  unsigned short* op = out + (size_t)blockIdx.z * outBS;
  const int r0 = blockIdx.y * 32, c0 = blockIdx.x * 32;
  const int tid = threadIdx.x;
  const int r = tid >> 3, c4 = (tid & 7) * 4;
  const f32x4 v = *(const f32x4*)(ip + (size_t)(r0 + r) * inRS + c0 + c4);
#pragma unroll
  for (int i = 0; i < 4; ++i) t[r][c4 + i] = v[i];
  __syncthreads();
  u16x4 o;
#pragma unroll
  for (int i = 0; i < 4; ++i) o[i] = f2bf(t[c4 + i][r]);
  *(u16x4*)(op + (size_t)(c0 + r) * outRS + r0 + c4) = o;
}

__global__ __launch_bounds__(256) void k_bias3(
    const float* __restrict__ a, const float* __restrict__ b,
    const float* __restrict__ c, float* __restrict__ o) {
  int i = blockIdx.x * 256 + threadIdx.x;
  if (i >= 3072) return;
  o[i] = (i < 1024) ? a[i] : ((i < 2048) ? b[i - 1024] : c[i - 2048]);
}

// ---------------- layernorm kernels ----------------
__global__ __launch_bounds__(256) void k_pre_ln(
    const float* __restrict__ X, const float* __restrict__ g,
    const float* __restrict__ bta, unsigned short* __restrict__ out) {
  __shared__ float red[4];
  const int row = blockIdx.x, tid = threadIdx.x;
  const f32x4 x = *(const f32x4*)(X + (size_t)row * 1024 + tid * 4);
  float s = x[0] + x[1] + x[2] + x[3];
  s = blk_sum(s, red, tid, 4);
  const float mean = s * (1.f / 1024.f);
  f32x4 d;
#pragma unroll
  for (int i = 0; i < 4; ++i) d[i] = x[i] - mean;
  float sq = d[0] * d[0] + d[1] * d[1] + d[2] * d[2] + d[3] * d[3];
  sq = blk_sum(sq, red, tid, 4);
  const float rstd = rsqrtf(sq * (1.f / 1024.f) + 1e-5f);
  const f32x4 gv = *(const f32x4*)(g + tid * 4);
  const f32x4 bv = *(const f32x4*)(bta + tid * 4);
  u16x4 o;
#pragma unroll
  for (int i = 0; i < 4; ++i) o[i] = f2bf(d[i] * rstd * gv[i] + bv[i]);
  *(u16x4*)(out + (size_t)row * 1024 + tid * 4) = o;
}

__global__ __launch_bounds__(256) void k_res_ln(
    const float* __restrict__ X, const unsigned short* __restrict__ attn,
    const float* __restrict__ g, const float* __restrict__ bta,
    float* __restrict__ X1, unsigned short* __restrict__ t2) {
  __shared__ float red[4];
  const int row = blockIdx.x, tid = threadIdx.x;
  const f32x4 x = *(const f32x4*)(X + (size_t)row * 1024 + tid * 4);
  const u16x4 a = *(const u16x4*)(attn + (size_t)row * 1024 + tid * 4);
  f32x4 x1;
#pragma unroll
  for (int i = 0; i < 4; ++i) x1[i] = x[i] + bf2f(a[i]);
  *(f32x4*)(X1 + (size_t)row * 1024 + tid * 4) = x1;
  float s = x1[0] + x1[1] + x1[2] + x1[3];
  s = blk_sum(s, red, tid, 4);
  const float mean = s * (1.f / 1024.f);
  f32x4 d;
#pragma unroll
  for (int i = 0; i < 4; ++i) d[i] = x1[i] - mean;
  float sq = d[0] * d[0] + d[1] * d[1] + d[2] * d[2] + d[3] * d[3];
  sq = blk_sum(sq, red, tid, 4);
  const float rstd = rsqrtf(sq * (1.f / 1024.f) + 1e-5f);
  const f32x4 gv = *(const f32x4*)(g + tid * 4);
  const f32x4 bv = *(const f32x4*)(bta + tid * 4);
  u16x4 o;
#pragma unroll
  for (int i = 0; i < 4; ++i) o[i] = f2bf(d[i] * rstd * gv[i] + bv[i]);
  *(u16x4*)(t2 + (size_t)row * 1024 + tid * 4) = o;
}

__global__ __launch_bounds__(256) void k_ln_gelu(
    const unsigned short* __restrict__ in, const float* __restrict__ g,
    const float* __restrict__ bta, unsigned short* __restrict__ out) {
  __shared__ float red[4];
  const int row = blockIdx.x, tid = threadIdx.x;
  const u16x8 iv = *(const u16x8*)(in + (size_t)row * 2048 + tid * 8);
  float v[8];
  float s = 0.f;
#pragma unroll
  for (int i = 0; i < 8; ++i) { v[i] = bf2f(iv[i]); s += v[i]; }
  s = blk_sum(s, red, tid, 4);
  const float mean = s * (1.f / 2048.f);
  float sq = 0.f;
#pragma unroll
  for (int i = 0; i < 8; ++i) { v[i] -= mean; sq += v[i] * v[i]; }
  sq = blk_sum(sq, red, tid, 4);
  const float rstd = rsqrtf(sq * (1.f / 2048.f) + 1e-5f);
  u16x8 o;
#pragma unroll
  for (int i = 0; i < 8; ++i) {
    float t = v[i] * rstd * g[tid * 8 + i] + bta[tid * 8 + i];
    o[i] = f2bf(gelu(t));
  }
  *(u16x8*)(out + (size_t)row * 2048 + tid * 8) = o;
}

__global__ __launch_bounds__(256) void k_final(
    const unsigned short* __restrict__ in, const float* __restrict__ g,
    const float* __restrict__ bta, float* __restrict__ io) {
  __shared__ float red[4];
  const int row = blockIdx.x, tid = threadIdx.x;
  const u16x4 iv = *(const u16x4*)(in + (size_t)row * 1024 + tid * 4);
  float v[4];
  float s = 0.f;
#pragma unroll
  for (int i = 0; i < 4; ++i) { v[i] = bf2f(iv[i]); s += v[i]; }
  s = blk_sum(s, red, tid, 4);
  const float mean = s * (1.f / 1024.f);
  float sq = 0.f;
#pragma unroll
  for (int i = 0; i < 4; ++i) { v[i] -= mean; sq += v[i] * v[i]; }
  sq = blk_sum(sq, red, tid, 4);
  const float rstd = rsqrtf(sq * (1.f / 1024.f) + 1e-5f);
  const f32x4 gv = *(const f32x4*)(g + tid * 4);
  const f32x4 bv = *(const f32x4*)(bta + tid * 4);
  f32x4 xi = *(const f32x4*)(io + (size_t)row * 1024 + tid * 4);
#pragma unroll
  for (int i = 0; i < 4; ++i)
    xi[i] += gelu(v[i] * rstd * gv[i] + bv[i]);
  *(f32x4*)(io + (size_t)row * 1024 + tid * 4) = xi;
}

// ---------------- GEMM: C_bf16[M][N] = A_bf16[M][K] @ Bt_bf16[N][K] + bias ----------------
// cols >= vsplit are written TRANSPOSED per-head into VtO[b][h][64][1024]
__global__ __launch_bounds__(256) void k_gemm(
    const unsigned short* __restrict__ A, const unsigned short* __restrict__ Bt,
    const float* __restrict__ bias, unsigned short* __restrict__ C,
    int M, int N, int K, int vsplit, unsigned short* __restrict__ VtO) {
  __shared__ __align__(16) unsigned short As[128 * 64];
  __shared__ __align__(16) unsigned short Bs[128 * 64];
  const int tid = threadIdx.x;
  const int w = tid >> 6, l = tid & 63;
  const int gx = gridDim.x;
  int flat = blockIdx.y * gx + blockIdx.x;
  const int nwg = gx * gridDim.y;
  if ((nwg & 7) == 0) flat = (flat & 7) * (nwg >> 3) + (flat >> 3);  // XCD swizzle
  const int m0 = (flat / gx) * 128, n0 = (flat % gx) * 128;
  const int wr = (w >> 1) * 64, wc = (w & 1) * 64;
  const f32x4 z4 = {0.f, 0.f, 0.f, 0.f};
  f32x4 acc[4][4];
#pragma unroll
  for (int i = 0; i < 4; ++i)
#pragma unroll
    for (int j = 0; j < 4; ++j) acc[i][j] = z4;

  const int srow = l >> 3, scol = (l & 7) * 8;
  for (int kt = 0; kt < K; kt += 64) {
#pragma unroll
    for (int i = 0; i < 4; ++i) {
      const int u = i * 4 + w;
      const int row = u * 8 + srow;
      gld16(A + (size_t)(m0 + row) * K + kt + scol, As + u * 512 + l * 8);
      gld16(Bt + (size_t)(n0 + row) * K + kt + scol, Bs + u * 512 + l * 8);
    }
    __syncthreads();
#pragma unroll
    for (int ks = 0; ks < 2; ++ks) {
      const int kb = ks * 32 + (l >> 4) * 8;
      s16x8 a[4], b[4];
#pragma unroll
      for (int m = 0; m < 4; ++m)
        a[m] = *(const s16x8*)(As + (wr + m * 16 + (l & 15)) * 64 + kb);
#pragma unroll
      for (int n = 0; n < 4; ++n)
        b[n] = *(const s16x8*)(Bs + (wc + n * 16 + (l & 15)) * 64 + kb);
#pragma unroll
      for (int m = 0; m < 4; ++m)
#pragma unroll
        for (int n = 0; n < 4; ++n)
          acc[m][n] = __builtin_amdgcn_mfma_f32_16x16x32_bf16(a[m], b[n], acc[m][n], 0, 0, 0);
    }
    __syncthreads();
  }
  const int rbase = m0 + wr + ((l >> 4) << 2);
  const int cbase = n0 + wc + (l & 15);
#pragma unroll
  for (int n = 0; n < 4; ++n) {
    const int c = cbase + n * 16;
    const float bb = bias[c];
    if ((n0 + wc + n * 16) < vsplit) {
#pragma unroll
      for (int m = 0; m < 4; ++m)
#pragma unroll
        for (int r = 0; r < 4; ++r)
          C[(size_t)(rbase + m * 16 + r) * N + c] = f2bf(acc[m][n][r] + bb);
    } else {  // V region -> transposed per-head write
      const int cc = c - vsplit;
      const int hh = cc >> 6, dd = cc & 63;
#pragma unroll
      for (int m = 0; m < 4; ++m) {
        const int rr = rbase + m * 16;
        u16x4 o;
#pragma unroll
        for (int r = 0; r < 4; ++r) o[r] = f2bf(acc[m][n][r] + bb);
        *(u16x4*)(VtO + ((size_t)((rr >> 10) * 16 + hh)) * 65536 + dd * 1024 + (rr & 1023)) = o;
      }
    }
  }
}

// ---------------- attention (no K/V LDS staging; barrier-free) ----------------
__device__ __forceinline__ int swz(int r, int c) {
  return r * 64 + (c ^ ((r & 7) << 3));
}

__global__ __launch_bounds__(256) void k_attn2(
    const unsigned short* __restrict__ qkv, const unsigned short* __restrict__ Vt,
    unsigned short* __restrict__ O) {
  int bid = blockIdx.x;
  bid = (bid & 7) * 256 + (bid >> 3);  // XCD swizzle (2048 blocks)
  const int qt = bid & 15, h = (bid >> 4) & 15, b = bid >> 8;
  const int tid = threadIdx.x, w = tid >> 6, l = tid & 63;
  const int arow = l & 15, kcol = (l >> 4) * 8;
  __shared__ __align__(16) unsigned short Ps[4][16 * 64];
  unsigned short* ps = &Ps[w][0];

  const unsigned short* qb = qkv + (size_t)b * 1024 * 3072 + h * 64;
  const unsigned short* kb = qb + 1024;
  const unsigned short* vt = Vt + ((size_t)(b * 16 + h)) * 65536;
  const int q0 = qt * 64 + w * 16;

  s16x8 qa[2];
#pragma unroll
  for (int kh = 0; kh < 2; ++kh)
    qa[kh] = *(const s16x8*)(qb + (size_t)(q0 + arow) * 3072 + kh * 32 + kcol);

  const f32x4 z4 = {0.f, 0.f, 0.f, 0.f};
  f32x4 oacc[4];
#pragma unroll
  for (int i = 0; i < 4; ++i) oacc[i] = z4;
  float mrun[4], lrun[4];
#pragma unroll
  for (int r = 0; r < 4; ++r) { mrun[r] = -1e30f; lrun[r] = 0.f; }

  const float c2 = 0.125f * 1.44269504088896f;  // exp2-domain scale

  for (int kc = 0; kc < 16; ++kc) {
    const int key0 = kc * 64;
    // QK^T: B-frags straight from global (L2-resident)
    f32x4 sacc[4];
#pragma unroll
    for (int t = 0; t < 4; ++t) {
      const unsigned short* kr = kb + (size_t)(key0 + t * 16 + arow) * 3072 + kcol;
      s16x8 k0 = *(const s16x8*)(kr);
      s16x8 k1 = *(const s16x8*)(kr + 32);
      f32x4 s = z4;
      s = __builtin_amdgcn_mfma_f32_16x16x32_bf16(qa[0], k0, s, 0, 0, 0);
      s = __builtin_amdgcn_mfma_f32_16x16x32_bf16(qa[1], k1, s, 0, 0, 0);
      sacc[t] = s;
    }
    float ss[4][4];
#pragma unroll
    for (int t = 0; t < 4; ++t)
#pragma unroll
      for (int r = 0; r < 4; ++r) ss[t][r] = sacc[t][r] * c2;

    float nm[4], sc[4], psum[4];
#pragma unroll
    for (int r = 0; r < 4; ++r) {
      float m = fmaxf(fmaxf(ss[0][r], ss[1][r]), fmaxf(ss[2][r], ss[3][r]));
#pragma unroll
      for (int msk = 8; msk >= 1; msk >>= 1) m = fmaxf(m, __shfl_xor(m, msk));
      nm[r] = fmaxf(mrun[r], m);
      sc[r] = fexp2(mrun[r] - nm[r]);
      mrun[r] = nm[r];
      psum[r] = 0.f;
    }
#pragma unroll
    for (int t = 0; t < 4; ++t)
#pragma unroll
      for (int r = 0; r < 4; ++r) {
        float p = fexp2(ss[t][r] - nm[r]);
        psum[r] += p;
        ps[swz(((l >> 4) << 2) + r, t * 16 + arow)] = f2bf(p);
      }
#pragma unroll
    for (int r = 0; r < 4; ++r) {
      float s = psum[r];
#pragma unroll
      for (int msk = 8; msk >= 1; msk >>= 1) s += __shfl_xor(s, msk);
      lrun[r] = lrun[r] * sc[r] + s;
#pragma unroll
      for (int dg = 0; dg < 4; ++dg) oacc[dg][r] *= sc[r];
    }
    s16x8 pa[2];
#pragma unroll
    for (int kh = 0; kh < 2; ++kh)
      pa[kh] = *(const s16x8*)(ps + swz(arow, kh * 32 + kcol));
    // PV: V^T B-frags straight from global
#pragma unroll
    for (int dg = 0; dg < 4; ++dg) {
      const unsigned short* vr = vt + (size_t)(dg * 16 + arow) * 1024 + key0 + kcol;
      s16x8 v0 = *(const s16x8*)(vr);
      s16x8 v1 = *(const s16x8*)(vr + 32);
      oacc[dg] = __builtin_amdgcn_mfma_f32_16x16x32_bf16(pa[0], v0, oacc[dg], 0, 0, 0);
      oacc[dg] = __builtin_amdgcn_mfma_f32_16x16x32_bf16(pa[1], v1, oacc[dg], 0, 0, 0);
    }
  }

  float inv[4];
#pragma unroll
  for (int r = 0; r < 4; ++r) inv[r] = 1.f / lrun[r];
#pragma unroll
  for (int dg = 0; dg < 4; ++dg)
#pragma unroll
    for (int r = 0; r < 4; ++r) {
      const int row = q0 + ((l >> 4) << 2) + r;
      O[(size_t)(b * 1024 + row) * 1024 + h * 64 + dg * 16 + arow] = f2bf(oacc[dg][r] * inv[r]);
    }
}

// ---------------- launcher ----------------
extern "C" void kernel_launch(void* const* d_in, const int* in_sizes, int n_in,
                              void* d_out, int out_size, void* d_ws, size_t ws_size,
                              hipStream_t stream) {
  const float* X = (const float*)d_in[0];
  const float* Wq = (const float*)d_in[1];
  const float* bq = (const float*)d_in[2];
  const float* Wk = (const float*)d_in[3];
  const float* bk = (const float*)d_in[4];
  const float* Wv = (const float*)d_in[5];
  const float* bv = (const float*)d_in[6];
  const float* pre_g = (const float*)d_in[7];
  const float* pre_b = (const float*)d_in[8];
  const float* post_g = (const float*)d_in[9];
  const float* post_b = (const float*)d_in[10];
  const float* W1 = (const float*)d_in[11];
  const float* b1 = (const float*)d_in[12];
  const float* ln1_g = (const float*)d_in[13];
  const float* ln1_b = (const float*)d_in[14];
  const float* W2 = (const float*)d_in[15];
  const float* b2 = (const float*)d_in[16];
  const float* ln2_g = (const float*)d_in[17];
  const float* ln2_b = (const float*)d_in[18];
  float* out = (float*)d_out;

  char* ws = (char*)d_ws;
  const size_t MB = (size_t)1 << 20;
  unsigned short* t_bf = (unsigned short*)(ws);             // [0,16)
  unsigned short* attn_o = (unsigned short*)(ws);           // [0,16) after t_bf dead
  unsigned short* mlp2 = (unsigned short*)(ws);             // [0,16) after attn_o dead
  unsigned short* qkv = (unsigned short*)(ws + 16 * MB);    // [16,64)
  unsigned short* mlp1 = (unsigned short*)(ws + 16 * MB);   // [16,48) after qkv dead
  unsigned short* Vt = (unsigned short*)(ws + 64 * MB);     // [64,80)
  unsigned short* h1 = (unsigned short*)(ws + 48 * MB);     // [48,80) after Vt dead
  unsigned short* t2 = (unsigned short*)(ws + 80 * MB);     // [80,96)
  unsigned short* Wqkvt = (unsigned short*)(ws + 96 * MB);  // [96,102)
  unsigned short* W1t = (unsigned short*)(ws + 102 * MB);   // [102,106)
  unsigned short* W2t = (unsigned short*)(ws + 106 * MB);   // [106,110)
  float* biasq = (float*)(ws + 110 * MB);

  // weight prep (tiled transposes, coalesced both sides)
  k_tr<<<dim3(2, 32, 16), 256, 0, stream>>>(Wq, Wqkvt, 64, 1024, 65536, 65536);
  k_tr<<<dim3(2, 32, 16), 256, 0, stream>>>(Wk, Wqkvt + 1048576, 64, 1024, 65536, 65536);
  k_tr<<<dim3(2, 32, 16), 256, 0, stream>>>(Wv, Wqkvt + 2097152, 64, 1024, 65536, 65536);
  k_tr<<<dim3(64, 32, 1), 256, 0, stream>>>(W1, W1t, 2048, 1024, 0, 0);
  k_tr<<<dim3(32, 64, 1), 256, 0, stream>>>(W2, W2t, 1024, 2048, 0, 0);
  k_bias3<<<12, 256, 0, stream>>>(bq, bk, bv, biasq);

  // pre-LN
  k_pre_ln<<<8192, 256, 0, stream>>>(X, pre_g, pre_b, t_bf);
  // QKV projection (V columns written transposed into Vt)
  k_gemm<<<dim3(24, 64), 256, 0, stream>>>(t_bf, Wqkvt, biasq, qkv, 8192, 3072, 1024, 2048, Vt);
  // attention
  k_attn2<<<2048, 256, 0, stream>>>(qkv, Vt, attn_o);
  // residual + post-LN (X1 stored in d_out)
  k_res_ln<<<8192, 256, 0, stream>>>(X, attn_o, post_g, post_b, out, t2);
  // MLP1
  k_gemm<<<dim3(16, 64), 256, 0, stream>>>(t2, W1t, b1, mlp1, 8192, 2048, 1024, 1 << 30, nullptr);
  k_ln_gelu<<<8192, 256, 0, stream>>>(mlp1, ln1_g, ln1_b, h1);
  // MLP2
  k_gemm<<<dim3(8, 64), 256, 0, stream>>>(h1, W2t, b2, mlp2, 8192, 1024, 2048, 1 << 30, nullptr);
  // final: out = X1 + gelu(LN(mlp2))
  k_final<<<8192, 256, 0, stream>>>(mlp2, ln2_g, ln2_b, out);
}

// Round 4
// 536.617 us; speedup vs baseline: 1.2323x; 1.2323x over previous
//
#include <hip/hip_runtime.h>

typedef __attribute__((ext_vector_type(8))) short s16x8;
typedef __attribute__((ext_vector_type(8))) unsigned short u16x8;
typedef __attribute__((ext_vector_type(4))) unsigned short u16x4;
typedef __attribute__((ext_vector_type(4))) float f32x4;

__device__ __forceinline__ unsigned short f2bf(float f) {
  union { float f; unsigned int u; } v; v.f = f;
  unsigned int r = (v.u + 0x7FFFu + ((v.u >> 16) & 1u)) >> 16;
  return (unsigned short)r;
}
__device__ __forceinline__ float bf2f(unsigned short h) {
  union { unsigned int u; float f; } v; v.u = ((unsigned int)h) << 16;
  return v.f;
}
__device__ __forceinline__ float gelu(float x) {
  return 0.5f * x * (1.f + erff(x * 0.70710678118654752f));
}
__device__ __forceinline__ float fexp2(float x) {
  float r; asm("v_exp_f32 %0, %1" : "=v"(r) : "v"(x)); return r;
}

__device__ __forceinline__ void gld16(const void* g, void* l) {
  __builtin_amdgcn_global_load_lds(
      (const __attribute__((address_space(1))) unsigned int*)g,
      (__attribute__((address_space(3))) unsigned int*)l, 16, 0, 0);
}

__device__ __forceinline__ float blk_sum(float v, float* red, int tid, int nw) {
#pragma unroll
  for (int m = 32; m >= 1; m >>= 1) v += __shfl_xor(v, m);
  __syncthreads();
  if ((tid & 63) == 0) red[tid >> 6] = v;
  __syncthreads();
  float t = 0.f;
  for (int i = 0; i < nw; ++i) t += red[i];
  return t;
}

// ---------------- tiled transpose: fp32 [R][C] -> bf16 [C][R], batched ----------------
__global__ __launch_bounds__(256) void k_tr(
    const float* __restrict__ in, unsigned short* __restrict__ out,
    int inRS, int outRS, long inBS, long outBS) {
  __shared__ float t[32][33];
  const float* ip = in + (size_t)blockIdx.z * inBS;
  unsigned short* op = out + (size_t)blockIdx.z * outBS;
  const int r0 = blockIdx.y * 32, c0 = blockIdx.x * 32;
  const int tid = threadIdx.x;
  const int r = tid >> 3, c4 = (tid & 7) * 4;
  const f32x4 v = *(const f32x4*)(ip + (size_t)(r0 + r) * inRS + c0 + c4);
#pragma unroll
  for (int i = 0; i < 4; ++i) t[r][c4 + i] = v[i];
  __syncthreads();
  u16x4 o;
#pragma unroll
  for (int i = 0; i < 4; ++i) o[i] = f2bf(t[c4 + i][r]);
  *(u16x4*)(op + (size_t)(c0 + r) * outRS + r0 + c4) = o;
}

__global__ __launch_bounds__(256) void k_bias3(
    const float* __restrict__ a, const float* __restrict__ b,
    const float* __restrict__ c, float* __restrict__ o) {
  int i = blockIdx.x * 256 + threadIdx.x;
  if (i >= 3072) return;
  o[i] = (i < 1024) ? a[i] : ((i < 2048) ? b[i - 1024] : c[i - 2048]);
}

// ---------------- layernorm kernels ----------------
__global__ __launch_bounds__(256) void k_pre_ln(
    const float* __restrict__ X, const float* __restrict__ g,
    const float* __restrict__ bta, unsigned short* __restrict__ out) {
  __shared__ float red[4];
  const int row = blockIdx.x, tid = threadIdx.x;
  const f32x4 x = *(const f32x4*)(X + (size_t)row * 1024 + tid * 4);
  float s = x[0] + x[1] + x[2] + x[3];
  s = blk_sum(s, red, tid, 4);
  const float mean = s * (1.f / 1024.f);
  f32x4 d;
#pragma unroll
  for (int i = 0; i < 4; ++i) d[i] = x[i] - mean;
  float sq = d[0] * d[0] + d[1] * d[1] + d[2] * d[2] + d[3] * d[3];
  sq = blk_sum(sq, red, tid, 4);
  const float rstd = rsqrtf(sq * (1.f / 1024.f) + 1e-5f);
  const f32x4 gv = *(const f32x4*)(g + tid * 4);
  const f32x4 bv = *(const f32x4*)(bta + tid * 4);
  u16x4 o;
#pragma unroll
  for (int i = 0; i < 4; ++i) o[i] = f2bf(d[i] * rstd * gv[i] + bv[i]);
  *(u16x4*)(out + (size_t)row * 1024 + tid * 4) = o;
}

__global__ __launch_bounds__(256) void k_res_ln(
    const float* __restrict__ X, const unsigned short* __restrict__ attn,
    const float* __restrict__ g, const float* __restrict__ bta,
    float* __restrict__ X1, unsigned short* __restrict__ t2) {
  __shared__ float red[4];
  const int row = blockIdx.x, tid = threadIdx.x;
  const f32x4 x = *(const f32x4*)(X + (size_t)row * 1024 + tid * 4);
  const u16x4 a = *(const u16x4*)(attn + (size_t)row * 1024 + tid * 4);
  f32x4 x1;
#pragma unroll
  for (int i = 0; i < 4; ++i) x1[i] = x[i] + bf2f(a[i]);
  *(f32x4*)(X1 + (size_t)row * 1024 + tid * 4) = x1;
  float s = x1[0] + x1[1] + x1[2] + x1[3];
  s = blk_sum(s, red, tid, 4);
  const float mean = s * (1.f / 1024.f);
  f32x4 d;
#pragma unroll
  for (int i = 0; i < 4; ++i) d[i] = x1[i] - mean;
  float sq = d[0] * d[0] + d[1] * d[1] + d[2] * d[2] + d[3] * d[3];
  sq = blk_sum(sq, red, tid, 4);
  const float rstd = rsqrtf(sq * (1.f / 1024.f) + 1e-5f);
  const f32x4 gv = *(const f32x4*)(g + tid * 4);
  const f32x4 bv = *(const f32x4*)(bta + tid * 4);
  u16x4 o;
#pragma unroll
  for (int i = 0; i < 4; ++i) o[i] = f2bf(d[i] * rstd * gv[i] + bv[i]);
  *(u16x4*)(t2 + (size_t)row * 1024 + tid * 4) = o;
}

__global__ __launch_bounds__(256) void k_ln_gelu(
    const unsigned short* __restrict__ in, const float* __restrict__ g,
    const float* __restrict__ bta, unsigned short* __restrict__ out) {
  __shared__ float red[4];
  const int row = blockIdx.x, tid = threadIdx.x;
  const u16x8 iv = *(const u16x8*)(in + (size_t)row * 2048 + tid * 8);
  float v[8];
  float s = 0.f;
#pragma unroll
  for (int i = 0; i < 8; ++i) { v[i] = bf2f(iv[i]); s += v[i]; }
  s = blk_sum(s, red, tid, 4);
  const float mean = s * (1.f / 2048.f);
  float sq = 0.f;
#pragma unroll
  for (int i = 0; i < 8; ++i) { v[i] -= mean; sq += v[i] * v[i]; }
  sq = blk_sum(sq, red, tid, 4);
  const float rstd = rsqrtf(sq * (1.f / 2048.f) + 1e-5f);
  u16x8 o;
#pragma unroll
  for (int i = 0; i < 8; ++i) {
    float t = v[i] * rstd * g[tid * 8 + i] + bta[tid * 8 + i];
    o[i] = f2bf(gelu(t));
  }
  *(u16x8*)(out + (size_t)row * 2048 + tid * 8) = o;
}

__global__ __launch_bounds__(256) void k_final(
    const unsigned short* __restrict__ in, const float* __restrict__ g,
    const float* __restrict__ bta, float* __restrict__ io) {
  __shared__ float red[4];
  const int row = blockIdx.x, tid = threadIdx.x;
  const u16x4 iv = *(const u16x4*)(in + (size_t)row * 1024 + tid * 4);
  float v[4];
  float s = 0.f;
#pragma unroll
  for (int i = 0; i < 4; ++i) { v[i] = bf2f(iv[i]); s += v[i]; }
  s = blk_sum(s, red, tid, 4);
  const float mean = s * (1.f / 1024.f);
  float sq = 0.f;
#pragma unroll
  for (int i = 0; i < 4; ++i) { v[i] -= mean; sq += v[i] * v[i]; }
  sq = blk_sum(sq, red, tid, 4);
  const float rstd = rsqrtf(sq * (1.f / 1024.f) + 1e-5f);
  const f32x4 gv = *(const f32x4*)(g + tid * 4);
  const f32x4 bv = *(const f32x4*)(bta + tid * 4);
  f32x4 xi = *(const f32x4*)(io + (size_t)row * 1024 + tid * 4);
#pragma unroll
  for (int i = 0; i < 4; ++i)
    xi[i] += gelu(v[i] * rstd * gv[i] + bv[i]);
  *(f32x4*)(io + (size_t)row * 1024 + tid * 4) = xi;
}

// ---------------- GEMM: C_bf16[M][N] = A_bf16[M][K] @ Bt_bf16[N][K] + bias ----------------
// cols >= vsplit are written TRANSPOSED per-head into VtO[b][h][64][1024]
__global__ __launch_bounds__(256) void k_gemm(
    const unsigned short* __restrict__ A, const unsigned short* __restrict__ Bt,
    const float* __restrict__ bias, unsigned short* __restrict__ C,
    int M, int N, int K, int vsplit, unsigned short* __restrict__ VtO) {
  __shared__ __align__(16) unsigned short As[128 * 64];
  __shared__ __align__(16) unsigned short Bs[128 * 64];
  const int tid = threadIdx.x;
  const int w = tid >> 6, l = tid & 63;
  const int gx = gridDim.x;
  int flat = blockIdx.y * gx + blockIdx.x;
  const int nwg = gx * gridDim.y;
  if ((nwg & 7) == 0) flat = (flat & 7) * (nwg >> 3) + (flat >> 3);  // XCD swizzle
  const int m0 = (flat / gx) * 128, n0 = (flat % gx) * 128;
  const int wr = (w >> 1) * 64, wc = (w & 1) * 64;
  const f32x4 z4 = {0.f, 0.f, 0.f, 0.f};
  f32x4 acc[4][4];
#pragma unroll
  for (int i = 0; i < 4; ++i)
#pragma unroll
    for (int j = 0; j < 4; ++j) acc[i][j] = z4;

  const int srow = l >> 3, scol = (l & 7) * 8;
  for (int kt = 0; kt < K; kt += 64) {
#pragma unroll
    for (int i = 0; i < 4; ++i) {
      const int u = i * 4 + w;
      const int row = u * 8 + srow;
      gld16(A + (size_t)(m0 + row) * K + kt + scol, As + u * 512 + l * 8);
      gld16(Bt + (size_t)(n0 + row) * K + kt + scol, Bs + u * 512 + l * 8);
    }
    __syncthreads();
#pragma unroll
    for (int ks = 0; ks < 2; ++ks) {
      const int kb = ks * 32 + (l >> 4) * 8;
      s16x8 a[4], b[4];
#pragma unroll
      for (int m = 0; m < 4; ++m)
        a[m] = *(const s16x8*)(As + (wr + m * 16 + (l & 15)) * 64 + kb);
#pragma unroll
      for (int n = 0; n < 4; ++n)
        b[n] = *(const s16x8*)(Bs + (wc + n * 16 + (l & 15)) * 64 + kb);
#pragma unroll
      for (int m = 0; m < 4; ++m)
#pragma unroll
        for (int n = 0; n < 4; ++n)
          acc[m][n] = __builtin_amdgcn_mfma_f32_16x16x32_bf16(a[m], b[n], acc[m][n], 0, 0, 0);
    }
    __syncthreads();
  }
  const int rbase = m0 + wr + ((l >> 4) << 2);
  const int cbase = n0 + wc + (l & 15);
#pragma unroll
  for (int n = 0; n < 4; ++n) {
    const int c = cbase + n * 16;
    const float bb = bias[c];
    if ((n0 + wc + n * 16) < vsplit) {
#pragma unroll
      for (int m = 0; m < 4; ++m)
#pragma unroll
        for (int r = 0; r < 4; ++r)
          C[(size_t)(rbase + m * 16 + r) * N + c] = f2bf(acc[m][n][r] + bb);
    } else {  // V region -> transposed per-head write
      const int cc = c - vsplit;
      const int hh = cc >> 6, dd = cc & 63;
#pragma unroll
      for (int m = 0; m < 4; ++m) {
        const int rr = rbase + m * 16;
        u16x4 o;
#pragma unroll
        for (int r = 0; r < 4; ++r) o[r] = f2bf(acc[m][n][r] + bb);
        *(u16x4*)(VtO + ((size_t)((rr >> 10) * 16 + hh)) * 65536 + dd * 1024 + (rr & 1023)) = o;
      }
    }
  }
}

// ---------------- attention v3: LDS-staged, double-buffered, swizzled ----------------
// elem-index swizzle: row of 64 bf16, XOR within-row 8-elem slot by (row&7)
__device__ __forceinline__ int swz(int r, int c) {
  return r * 64 + (c ^ ((r & 7) << 3));
}

__global__ __launch_bounds__(256) void k_attn3(
    const unsigned short* __restrict__ qkv, const unsigned short* __restrict__ Vt,
    unsigned short* __restrict__ O) {
  int bid = blockIdx.x;
  bid = (bid & 7) * 256 + (bid >> 3);  // XCD swizzle (2048 blocks)
  const int qt = bid & 15, h = (bid >> 4) & 15, b = bid >> 8;
  const int tid = threadIdx.x, w = tid >> 6, l = tid & 63;
  const int arow = l & 15, kcol = (l >> 4) * 8;

  __shared__ __align__(16) unsigned short Kb[2][64 * 64];
  __shared__ __align__(16) unsigned short Vb[2][64 * 64];
  __shared__ __align__(16) unsigned short Ps[4][16 * 64];
  unsigned short* ps = &Ps[w][0];

  const unsigned short* qb = qkv + (size_t)b * 1024 * 3072 + h * 64;
  const unsigned short* kb = qb + 1024;
  const unsigned short* vt = Vt + ((size_t)(b * 16 + h)) * 65536;
  const int q0 = qt * 64 + w * 16;

  // Q fragments (one-time, direct from global)
  s16x8 qa[2];
#pragma unroll
  for (int kh = 0; kh < 2; ++kh)
    qa[kh] = *(const s16x8*)(qb + (size_t)(q0 + arow) * 3072 + kh * 32 + kcol);

  // staging geometry: lane tid covers LDS linear slot tid*16B of an issue
  const int srow = tid >> 3;                       // 0..31 (row within 32-row half)
  const int sce = 8 * ((tid & 7) ^ (srow & 7));    // pre-swizzled source col (elems)
  const int sdst = srow * 64 + (tid & 7) * 8;      // linear LDS dest (elems)

  // prologue: stage kc=0 into buffer 0
#pragma unroll
  for (int i = 0; i < 2; ++i) {
    gld16(kb + (size_t)(i * 32 + srow) * 3072 + sce, Kb[0] + i * 2048 + sdst);
    gld16(vt + (size_t)(i * 32 + srow) * 1024 + sce, Vb[0] + i * 2048 + sdst);
  }
  __syncthreads();

  const f32x4 z4 = {0.f, 0.f, 0.f, 0.f};
  f32x4 oacc[4];
#pragma unroll
  for (int i = 0; i < 4; ++i) oacc[i] = z4;
  float mrun[4], lrun[4];
#pragma unroll
  for (int r = 0; r < 4; ++r) { mrun[r] = -1e30f; lrun[r] = 0.f; }

  const float c2 = 0.125f * 1.44269504088896f;  // exp2-domain scale

  for (int kc = 0; kc < 16; ++kc) {
    const int cur = kc & 1;
    // issue async stage of next tile (overlaps with compute below)
    if (kc < 15) {
      const int key1 = (kc + 1) * 64;
#pragma unroll
      for (int i = 0; i < 2; ++i) {
        gld16(kb + (size_t)(key1 + i * 32 + srow) * 3072 + sce, Kb[cur ^ 1] + i * 2048 + sdst);
        gld16(vt + (size_t)(i * 32 + srow) * 1024 + key1 + sce, Vb[cur ^ 1] + i * 2048 + sdst);
      }
    }
    // QK^T from staged K
    f32x4 sacc[4];
#pragma unroll
    for (int t = 0; t < 4; ++t) {
      s16x8 k0 = *(const s16x8*)(Kb[cur] + swz(t * 16 + arow, kcol));
      s16x8 k1 = *(const s16x8*)(Kb[cur] + swz(t * 16 + arow, 32 + kcol));
      f32x4 s = z4;
      s = __builtin_amdgcn_mfma_f32_16x16x32_bf16(qa[0], k0, s, 0, 0, 0);
      s = __builtin_amdgcn_mfma_f32_16x16x32_bf16(qa[1], k1, s, 0, 0, 0);
      sacc[t] = s;
    }
    float ss[4][4];
#pragma unroll
    for (int t = 0; t < 4; ++t)
#pragma unroll
      for (int r = 0; r < 4; ++r) ss[t][r] = sacc[t][r] * c2;

    float nm[4], sc[4], psum[4];
#pragma unroll
    for (int r = 0; r < 4; ++r) {
      float m = fmaxf(fmaxf(ss[0][r], ss[1][r]), fmaxf(ss[2][r], ss[3][r]));
#pragma unroll
      for (int msk = 8; msk >= 1; msk >>= 1) m = fmaxf(m, __shfl_xor(m, msk));
      nm[r] = fmaxf(mrun[r], m);
      sc[r] = fexp2(mrun[r] - nm[r]);
      mrun[r] = nm[r];
      psum[r] = 0.f;
    }
#pragma unroll
    for (int t = 0; t < 4; ++t)
#pragma unroll
      for (int r = 0; r < 4; ++r) {
        float p = fexp2(ss[t][r] - nm[r]);
        psum[r] += p;
        ps[swz(((l >> 4) << 2) + r, t * 16 + arow)] = f2bf(p);
      }
#pragma unroll
    for (int r = 0; r < 4; ++r) {
      float s = psum[r];
#pragma unroll
      for (int msk = 8; msk >= 1; msk >>= 1) s += __shfl_xor(s, msk);
      lrun[r] = lrun[r] * sc[r] + s;
#pragma unroll
      for (int dg = 0; dg < 4; ++dg) oacc[dg][r] *= sc[r];
    }
    s16x8 pa[2];
#pragma unroll
    for (int kh = 0; kh < 2; ++kh)
      pa[kh] = *(const s16x8*)(ps + swz(arow, kh * 32 + kcol));
    // PV from staged V^T
#pragma unroll
    for (int dg = 0; dg < 4; ++dg) {
      s16x8 v0 = *(const s16x8*)(Vb[cur] + swz(dg * 16 + arow, kcol));
      s16x8 v1 = *(const s16x8*)(Vb[cur] + swz(dg * 16 + arow, 32 + kcol));
      oacc[dg] = __builtin_amdgcn_mfma_f32_16x16x32_bf16(pa[0], v0, oacc[dg], 0, 0, 0);
      oacc[dg] = __builtin_amdgcn_mfma_f32_16x16x32_bf16(pa[1], v1, oacc[dg], 0, 0, 0);
    }
    __syncthreads();  // drains stage loads; next buffer ready, this buffer free
  }

  float inv[4];
#pragma unroll
  for (int r = 0; r < 4; ++r) inv[r] = 1.f / lrun[r];
#pragma unroll
  for (int dg = 0; dg < 4; ++dg)
#pragma unroll
    for (int r = 0; r < 4; ++r) {
      const int row = q0 + ((l >> 4) << 2) + r;
      O[(size_t)(b * 1024 + row) * 1024 + h * 64 + dg * 16 + arow] = f2bf(oacc[dg][r] * inv[r]);
    }
}

// ---------------- launcher ----------------
extern "C" void kernel_launch(void* const* d_in, const int* in_sizes, int n_in,
                              void* d_out, int out_size, void* d_ws, size_t ws_size,
                              hipStream_t stream) {
  const float* X = (const float*)d_in[0];
  const float* Wq = (const float*)d_in[1];
  const float* bq = (const float*)d_in[2];
  const float* Wk = (const float*)d_in[3];
  const float* bk = (const float*)d_in[4];
  const float* Wv = (const float*)d_in[5];
  const float* bv = (const float*)d_in[6];
  const float* pre_g = (const float*)d_in[7];
  const float* pre_b = (const float*)d_in[8];
  const float* post_g = (const float*)d_in[9];
  const float* post_b = (const float*)d_in[10];
  const float* W1 = (const float*)d_in[11];
  const float* b1 = (const float*)d_in[12];
  const float* ln1_g = (const float*)d_in[13];
  const float* ln1_b = (const float*)d_in[14];
  const float* W2 = (const float*)d_in[15];
  const float* b2 = (const float*)d_in[16];
  const float* ln2_g = (const float*)d_in[17];
  const float* ln2_b = (const float*)d_in[18];
  float* out = (float*)d_out;

  char* ws = (char*)d_ws;
  const size_t MB = (size_t)1 << 20;
  unsigned short* t_bf = (unsigned short*)(ws);             // [0,16)
  unsigned short* attn_o = (unsigned short*)(ws);           // [0,16) after t_bf dead
  unsigned short* mlp2 = (unsigned short*)(ws);             // [0,16) after attn_o dead
  unsigned short* qkv = (unsigned short*)(ws + 16 * MB);    // [16,64)
  unsigned short* mlp1 = (unsigned short*)(ws + 16 * MB);   // [16,48) after qkv dead
  unsigned short* Vt = (unsigned short*)(ws + 64 * MB);     // [64,80)
  unsigned short* h1 = (unsigned short*)(ws + 48 * MB);     // [48,80) after Vt dead
  unsigned short* t2 = (unsigned short*)(ws + 80 * MB);     // [80,96)
  unsigned short* Wqkvt = (unsigned short*)(ws + 96 * MB);  // [96,102)
  unsigned short* W1t = (unsigned short*)(ws + 102 * MB);   // [102,106)
  unsigned short* W2t = (unsigned short*)(ws + 106 * MB);   // [106,110)
  float* biasq = (float*)(ws + 110 * MB);

  // weight prep (tiled transposes, coalesced both sides)
  k_tr<<<dim3(2, 32, 16), 256, 0, stream>>>(Wq, Wqkvt, 64, 1024, 65536, 65536);
  k_tr<<<dim3(2, 32, 16), 256, 0, stream>>>(Wk, Wqkvt + 1048576, 64, 1024, 65536, 65536);
  k_tr<<<dim3(2, 32, 16), 256, 0, stream>>>(Wv, Wqkvt + 2097152, 64, 1024, 65536, 65536);
  k_tr<<<dim3(64, 32, 1), 256, 0, stream>>>(W1, W1t, 2048, 1024, 0, 0);
  k_tr<<<dim3(32, 64, 1), 256, 0, stream>>>(W2, W2t, 1024, 2048, 0, 0);
  k_bias3<<<12, 256, 0, stream>>>(bq, bk, bv, biasq);

  // pre-LN
  k_pre_ln<<<8192, 256, 0, stream>>>(X, pre_g, pre_b, t_bf);
  // QKV projection (V columns written transposed into Vt)
  k_gemm<<<dim3(24, 64), 256, 0, stream>>>(t_bf, Wqkvt, biasq, qkv, 8192, 3072, 1024, 2048, Vt);
  // attention
  k_attn3<<<2048, 256, 0, stream>>>(qkv, Vt, attn_o);
  // residual + post-LN (X1 stored in d_out)
  k_res_ln<<<8192, 256, 0, stream>>>(X, attn_o, post_g, post_b, out, t2);
  // MLP1
  k_gemm<<<dim3(16, 64), 256, 0, stream>>>(t2, W1t, b1, mlp1, 8192, 2048, 1024, 1 << 30, nullptr);
  k_ln_gelu<<<8192, 256, 0, stream>>>(mlp1, ln1_g, ln1_b, h1);
  // MLP2
  k_gemm<<<dim3(8, 64), 256, 0, stream>>>(h1, W2t, b2, mlp2, 8192, 1024, 2048, 1 << 30, nullptr);
  // final: out = X1 + gelu(LN(mlp2))
  k_final<<<8192, 256, 0, stream>>>(mlp2, ln2_g, ln2_b, out);
}

// Round 5
// 519.067 us; speedup vs baseline: 1.2740x; 1.0338x over previous
//
#include <hip/hip_runtime.h>

typedef __attribute__((ext_vector_type(8))) short s16x8;
typedef __attribute__((ext_vector_type(8))) unsigned short u16x8;
typedef __attribute__((ext_vector_type(4))) unsigned short u16x4;
typedef __attribute__((ext_vector_type(4))) float f32x4;

__device__ __forceinline__ unsigned short f2bf(float f) {
  union { float f; unsigned int u; } v; v.f = f;
  unsigned int r = (v.u + 0x7FFFu + ((v.u >> 16) & 1u)) >> 16;
  return (unsigned short)r;
}
__device__ __forceinline__ float bf2f(unsigned short h) {
  union { unsigned int u; float f; } v; v.u = ((unsigned int)h) << 16;
  return v.f;
}
__device__ __forceinline__ float gelu(float x) {
  return 0.5f * x * (1.f + erff(x * 0.70710678118654752f));
}
__device__ __forceinline__ float fexp2(float x) {
  float r; asm("v_exp_f32 %0, %1" : "=v"(r) : "v"(x)); return r;
}

__device__ __forceinline__ void gld16(const void* g, void* l) {
  __builtin_amdgcn_global_load_lds(
      (const __attribute__((address_space(1))) unsigned int*)g,
      (__attribute__((address_space(3))) unsigned int*)l, 16, 0, 0);
}

__device__ __forceinline__ float blk_sum(float v, float* red, int tid, int nw) {
#pragma unroll
  for (int m = 32; m >= 1; m >>= 1) v += __shfl_xor(v, m);
  __syncthreads();
  if ((tid & 63) == 0) red[tid >> 6] = v;
  __syncthreads();
  float t = 0.f;
  for (int i = 0; i < nw; ++i) t += red[i];
  return t;
}

// ---------------- tiled transpose: fp32 [R][C] -> bf16 [C][R], batched ----------------
__global__ __launch_bounds__(256) void k_tr(
    const float* __restrict__ in, unsigned short* __restrict__ out,
    int inRS, int outRS, long inBS, long outBS) {
  __shared__ float t[32][33];
  const float* ip = in + (size_t)blockIdx.z * inBS;
  unsigned short* op = out + (size_t)blockIdx.z * outBS;
  const int r0 = blockIdx.y * 32, c0 = blockIdx.x * 32;
  const int tid = threadIdx.x;
  const int r = tid >> 3, c4 = (tid & 7) * 4;
  const f32x4 v = *(const f32x4*)(ip + (size_t)(r0 + r) * inRS + c0 + c4);
#pragma unroll
  for (int i = 0; i < 4; ++i) t[r][c4 + i] = v[i];
  __syncthreads();
  u16x4 o;
#pragma unroll
  for (int i = 0; i < 4; ++i) o[i] = f2bf(t[c4 + i][r]);
  *(u16x4*)(op + (size_t)(c0 + r) * outRS + r0 + c4) = o;
}

__global__ __launch_bounds__(256) void k_bias3(
    const float* __restrict__ a, const float* __restrict__ b,
    const float* __restrict__ c, float* __restrict__ o) {
  int i = blockIdx.x * 256 + threadIdx.x;
  if (i >= 3072) return;
  o[i] = (i < 1024) ? a[i] : ((i < 2048) ? b[i - 1024] : c[i - 2048]);
}

// ---------------- layernorm kernels ----------------
__global__ __launch_bounds__(256) void k_pre_ln(
    const float* __restrict__ X, const float* __restrict__ g,
    const float* __restrict__ bta, unsigned short* __restrict__ out) {
  __shared__ float red[4];
  const int row = blockIdx.x, tid = threadIdx.x;
  const f32x4 x = *(const f32x4*)(X + (size_t)row * 1024 + tid * 4);
  float s = x[0] + x[1] + x[2] + x[3];
  s = blk_sum(s, red, tid, 4);
  const float mean = s * (1.f / 1024.f);
  f32x4 d;
#pragma unroll
  for (int i = 0; i < 4; ++i) d[i] = x[i] - mean;
  float sq = d[0] * d[0] + d[1] * d[1] + d[2] * d[2] + d[3] * d[3];
  sq = blk_sum(sq, red, tid, 4);
  const float rstd = rsqrtf(sq * (1.f / 1024.f) + 1e-5f);
  const f32x4 gv = *(const f32x4*)(g + tid * 4);
  const f32x4 bv = *(const f32x4*)(bta + tid * 4);
  u16x4 o;
#pragma unroll
  for (int i = 0; i < 4; ++i) o[i] = f2bf(d[i] * rstd * gv[i] + bv[i]);
  *(u16x4*)(out + (size_t)row * 1024 + tid * 4) = o;
}

__global__ __launch_bounds__(256) void k_res_ln(
    const float* __restrict__ X, const unsigned short* __restrict__ attn,
    const float* __restrict__ g, const float* __restrict__ bta,
    float* __restrict__ X1, unsigned short* __restrict__ t2) {
  __shared__ float red[4];
  const int row = blockIdx.x, tid = threadIdx.x;
  const f32x4 x = *(const f32x4*)(X + (size_t)row * 1024 + tid * 4);
  const u16x4 a = *(const u16x4*)(attn + (size_t)row * 1024 + tid * 4);
  f32x4 x1;
#pragma unroll
  for (int i = 0; i < 4; ++i) x1[i] = x[i] + bf2f(a[i]);
  *(f32x4*)(X1 + (size_t)row * 1024 + tid * 4) = x1;
  float s = x1[0] + x1[1] + x1[2] + x1[3];
  s = blk_sum(s, red, tid, 4);
  const float mean = s * (1.f / 1024.f);
  f32x4 d;
#pragma unroll
  for (int i = 0; i < 4; ++i) d[i] = x1[i] - mean;
  float sq = d[0] * d[0] + d[1] * d[1] + d[2] * d[2] + d[3] * d[3];
  sq = blk_sum(sq, red, tid, 4);
  const float rstd = rsqrtf(sq * (1.f / 1024.f) + 1e-5f);
  const f32x4 gv = *(const f32x4*)(g + tid * 4);
  const f32x4 bv = *(const f32x4*)(bta + tid * 4);
  u16x4 o;
#pragma unroll
  for (int i = 0; i < 4; ++i) o[i] = f2bf(d[i] * rstd * gv[i] + bv[i]);
  *(u16x4*)(t2 + (size_t)row * 1024 + tid * 4) = o;
}

__global__ __launch_bounds__(256) void k_ln_gelu(
    const unsigned short* __restrict__ in, const float* __restrict__ g,
    const float* __restrict__ bta, unsigned short* __restrict__ out) {
  __shared__ float red[4];
  const int row = blockIdx.x, tid = threadIdx.x;
  const u16x8 iv = *(const u16x8*)(in + (size_t)row * 2048 + tid * 8);
  float v[8];
  float s = 0.f;
#pragma unroll
  for (int i = 0; i < 8; ++i) { v[i] = bf2f(iv[i]); s += v[i]; }
  s = blk_sum(s, red, tid, 4);
  const float mean = s * (1.f / 2048.f);
  float sq = 0.f;
#pragma unroll
  for (int i = 0; i < 8; ++i) { v[i] -= mean; sq += v[i] * v[i]; }
  sq = blk_sum(sq, red, tid, 4);
  const float rstd = rsqrtf(sq * (1.f / 2048.f) + 1e-5f);
  u16x8 o;
#pragma unroll
  for (int i = 0; i < 8; ++i) {
    float t = v[i] * rstd * g[tid * 8 + i] + bta[tid * 8 + i];
    o[i] = f2bf(gelu(t));
  }
  *(u16x8*)(out + (size_t)row * 2048 + tid * 8) = o;
}

__global__ __launch_bounds__(256) void k_final(
    const unsigned short* __restrict__ in, const float* __restrict__ g,
    const float* __restrict__ bta, float* __restrict__ io) {
  __shared__ float red[4];
  const int row = blockIdx.x, tid = threadIdx.x;
  const u16x4 iv = *(const u16x4*)(in + (size_t)row * 1024 + tid * 4);
  float v[4];
  float s = 0.f;
#pragma unroll
  for (int i = 0; i < 4; ++i) { v[i] = bf2f(iv[i]); s += v[i]; }
  s = blk_sum(s, red, tid, 4);
  const float mean = s * (1.f / 1024.f);
  float sq = 0.f;
#pragma unroll
  for (int i = 0; i < 4; ++i) { v[i] -= mean; sq += v[i] * v[i]; }
  sq = blk_sum(sq, red, tid, 4);
  const float rstd = rsqrtf(sq * (1.f / 1024.f) + 1e-5f);
  const f32x4 gv = *(const f32x4*)(g + tid * 4);
  const f32x4 bv = *(const f32x4*)(bta + tid * 4);
  f32x4 xi = *(const f32x4*)(io + (size_t)row * 1024 + tid * 4);
#pragma unroll
  for (int i = 0; i < 4; ++i)
    xi[i] += gelu(v[i] * rstd * gv[i] + bv[i]);
  *(f32x4*)(io + (size_t)row * 1024 + tid * 4) = xi;
}

// ---------------- GEMM v2: BM=256 BN=128 BK=64, 512 thr, 3-deep counted-vmcnt pipe ----
// C_bf16[M][N] = A_bf16[M][K] @ Bt_bf16[N][K] + bias; cols >= vsplit -> VtO transposed
// LDS per buffer: A 256x64 (32KB) + B 128x64 (16KB); 3 buffers = 144KB (dynamic)
__global__ __launch_bounds__(512) void k_gemm2(
    const unsigned short* __restrict__ A, const unsigned short* __restrict__ Bt,
    const float* __restrict__ bias, unsigned short* __restrict__ C,
    int M, int N, int K, int vsplit, unsigned short* __restrict__ VtO) {
  extern __shared__ __align__(16) unsigned short lds[];  // 3 * 24576 elems
  const int tid = threadIdx.x;
  const int w = tid >> 6, l = tid & 63;
  const int wm = w >> 1, wn = w & 1;  // 4 M-waves x 2 N-waves
  const int gx = gridDim.x;
  int flat = blockIdx.y * gx + blockIdx.x;
  const int nwg = gx * gridDim.y;
  if ((nwg & 7) == 0) flat = (flat & 7) * (nwg >> 3) + (flat >> 3);  // XCD swizzle
  const int m0 = (flat / gx) * 256, n0 = (flat % gx) * 128;

  const f32x4 z4 = {0.f, 0.f, 0.f, 0.f};
  f32x4 acc[4][4];
#pragma unroll
  for (int i = 0; i < 4; ++i)
#pragma unroll
    for (int j = 0; j < 4; ++j) acc[i][j] = z4;

  // staging: slot s covers LDS elems [s*8, s*8+8); src col pre-swizzled (rule #21)
#define STAGE_G2(t, d)                                                              \
  {                                                                                 \
    const int kb = (t) * 64;                                                        \
    _Pragma("unroll") for (int i = 0; i < 4; ++i) {                                 \
      const int s = i * 512 + tid;                                                  \
      const int row = s >> 3, cs = s & 7;                                           \
      gld16(A + (size_t)(m0 + row) * K + kb + ((cs ^ (row & 7)) << 3),              \
            lds + (d) * 24576 + s * 8);                                             \
    }                                                                               \
    _Pragma("unroll") for (int i = 0; i < 2; ++i) {                                 \
      const int s = i * 512 + tid;                                                  \
      const int row = s >> 3, cs = s & 7;                                           \
      gld16(Bt + (size_t)(n0 + row) * K + kb + ((cs ^ (row & 7)) << 3),             \
            lds + (d) * 24576 + 16384 + s * 8);                                     \
    }                                                                               \
  }

  const int nt = K >> 6;
  STAGE_G2(0, 0);
  STAGE_G2(1, 1);

  for (int t = 0; t < nt; ++t) {
    const int d = t % 3;
    if (t + 2 < nt) {
      const int d2 = (t + 2) % 3;
      STAGE_G2(t + 2, d2);
      asm volatile("s_waitcnt vmcnt(12)" ::: "memory");  // tile t done; t+1,t+2 in flight
    } else if (t + 1 < nt) {
      asm volatile("s_waitcnt vmcnt(6)" ::: "memory");
    } else {
      asm volatile("s_waitcnt vmcnt(0)" ::: "memory");
    }
    __syncthreads();

    const unsigned short* Ab = lds + d * 24576;
    const unsigned short* Bb = Ab + 16384;
    __builtin_amdgcn_s_setprio(1);
#pragma unroll
    for (int ks = 0; ks < 2; ++ks) {
      const int cs = ks * 4 + (l >> 4);
      s16x8 a[4], b[4];
#pragma unroll
      for (int m = 0; m < 4; ++m) {
        const int row = wm * 64 + m * 16 + (l & 15);
        a[m] = *(const s16x8*)(Ab + row * 64 + ((cs ^ (row & 7)) << 3));
      }
#pragma unroll
      for (int n = 0; n < 4; ++n) {
        const int row = wn * 64 + n * 16 + (l & 15);
        b[n] = *(const s16x8*)(Bb + row * 64 + ((cs ^ (row & 7)) << 3));
      }
#pragma unroll
      for (int m = 0; m < 4; ++m)
#pragma unroll
        for (int n = 0; n < 4; ++n)
          acc[m][n] = __builtin_amdgcn_mfma_f32_16x16x32_bf16(a[m], b[n], acc[m][n], 0, 0, 0);
    }
    __builtin_amdgcn_s_setprio(0);
    __syncthreads();  // all waves done reading buf d -> free for tile t+3
  }
#undef STAGE_G2

  const int rbase = m0 + wm * 64 + ((l >> 4) << 2);
  const int cbase = n0 + wn * 64 + (l & 15);
#pragma unroll
  for (int n = 0; n < 4; ++n) {
    const int c = cbase + n * 16;
    const float bb = bias[c];
    if ((n0 + wn * 64 + n * 16) < vsplit) {
#pragma unroll
      for (int m = 0; m < 4; ++m)
#pragma unroll
        for (int r = 0; r < 4; ++r)
          C[(size_t)(rbase + m * 16 + r) * N + c] = f2bf(acc[m][n][r] + bb);
    } else {  // V region -> transposed per-head write
      const int cc = c - vsplit;
      const int hh = cc >> 6, dd = cc & 63;
#pragma unroll
      for (int m = 0; m < 4; ++m) {
        const int rr = rbase + m * 16;
        u16x4 o;
#pragma unroll
        for (int r = 0; r < 4; ++r) o[r] = f2bf(acc[m][n][r] + bb);
        *(u16x4*)(VtO + ((size_t)((rr >> 10) * 16 + hh)) * 65536 + dd * 1024 + (rr & 1023)) = o;
      }
    }
  }
}

// ---------------- attention: LDS-staged dbuf + scaled-Q + ones-trick + defer-max ----
__device__ __forceinline__ int swz(int r, int c) {
  return r * 64 + (c ^ ((r & 7) << 3));
}

__global__ __launch_bounds__(256) void k_attn3(
    const unsigned short* __restrict__ qkv, const unsigned short* __restrict__ Vt,
    unsigned short* __restrict__ O) {
  int bid = blockIdx.x;
  bid = (bid & 7) * 256 + (bid >> 3);  // XCD swizzle (2048 blocks)
  const int qt = bid & 15, h = (bid >> 4) & 15, b = bid >> 8;
  const int tid = threadIdx.x, w = tid >> 6, l = tid & 63;
  const int arow = l & 15, kcol = (l >> 4) * 8;

  __shared__ __align__(16) unsigned short Kb[2][64 * 64];
  __shared__ __align__(16) unsigned short Vb[2][64 * 64];
  __shared__ __align__(16) unsigned short Ps[4][16 * 64];
  unsigned short* ps = &Ps[w][0];

  const unsigned short* qb = qkv + (size_t)b * 1024 * 3072 + h * 64;
  const unsigned short* kb = qb + 1024;
  const unsigned short* vt = Vt + ((size_t)(b * 16 + h)) * 65536;
  const int q0 = qt * 64 + w * 16;

  const float c2 = 0.125f * 1.44269504088896f;  // exp2-domain scale, folded into Q

  // Q fragments, pre-scaled by c2 (one-time)
  s16x8 qa[2];
#pragma unroll
  for (int kh = 0; kh < 2; ++kh) {
    s16x8 q = *(const s16x8*)(qb + (size_t)(q0 + arow) * 3072 + kh * 32 + kcol);
#pragma unroll
    for (int j = 0; j < 8; ++j)
      q[j] = (short)f2bf(bf2f((unsigned short)q[j]) * c2);
    qa[kh] = q;
  }
  s16x8 ones;
#pragma unroll
  for (int j = 0; j < 8; ++j) ones[j] = (short)0x3F80;  // bf16 1.0

  const int srow = tid >> 3;
  const int sce = 8 * ((tid & 7) ^ (srow & 7));
  const int sdst = srow * 64 + (tid & 7) * 8;

#pragma unroll
  for (int i = 0; i < 2; ++i) {
    gld16(kb + (size_t)(i * 32 + srow) * 3072 + sce, Kb[0] + i * 2048 + sdst);
    gld16(vt + (size_t)(i * 32 + srow) * 1024 + sce, Vb[0] + i * 2048 + sdst);
  }
  __syncthreads();

  const f32x4 z4 = {0.f, 0.f, 0.f, 0.f};
  f32x4 oacc[4];
#pragma unroll
  for (int i = 0; i < 4; ++i) oacc[i] = z4;
  f32x4 lacc = z4;
  float mrun[4];
#pragma unroll
  for (int r = 0; r < 4; ++r) mrun[r] = -1e30f;

  for (int kc = 0; kc < 16; ++kc) {
    const int cur = kc & 1;
    if (kc < 15) {
      const int key1 = (kc + 1) * 64;
#pragma unroll
      for (int i = 0; i < 2; ++i) {
        gld16(kb + (size_t)(key1 + i * 32 + srow) * 3072 + sce, Kb[cur ^ 1] + i * 2048 + sdst);
        gld16(vt + (size_t)(i * 32 + srow) * 1024 + key1 + sce, Vb[cur ^ 1] + i * 2048 + sdst);
      }
    }
    // QK^T (S pre-scaled to exp2 domain via Q)
    f32x4 sacc[4];
#pragma unroll
    for (int t = 0; t < 4; ++t) {
      s16x8 k0 = *(const s16x8*)(Kb[cur] + swz(t * 16 + arow, kcol));
      s16x8 k1 = *(const s16x8*)(Kb[cur] + swz(t * 16 + arow, 32 + kcol));
      f32x4 s = z4;
      s = __builtin_amdgcn_mfma_f32_16x16x32_bf16(qa[0], k0, s, 0, 0, 0);
      s = __builtin_amdgcn_mfma_f32_16x16x32_bf16(qa[1], k1, s, 0, 0, 0);
      sacc[t] = s;
    }
    float rmax[4];
#pragma unroll
    for (int r = 0; r < 4; ++r) {
      float m = fmaxf(fmaxf(sacc[0][r], sacc[1][r]), fmaxf(sacc[2][r], sacc[3][r]));
#pragma unroll
      for (int msk = 8; msk >= 1; msk >>= 1) m = fmaxf(m, __shfl_xor(m, msk));
      rmax[r] = m;
    }
    // defer-max (T13): rescale only when some row grew by > 8 (P bounded by 2^8)
    const float need = fmaxf(fmaxf(rmax[0] - mrun[0], rmax[1] - mrun[1]),
                             fmaxf(rmax[2] - mrun[2], rmax[3] - mrun[3]));
    if (!__all(need <= 8.f)) {
      float sc[4];
#pragma unroll
      for (int r = 0; r < 4; ++r) {
        const float nm = fmaxf(mrun[r], rmax[r]);
        sc[r] = fexp2(mrun[r] - nm);
        mrun[r] = nm;
      }
#pragma unroll
      for (int r = 0; r < 4; ++r) {
        lacc[r] *= sc[r];
#pragma unroll
        for (int dg = 0; dg < 4; ++dg) oacc[dg][r] *= sc[r];
      }
    }
#pragma unroll
    for (int t = 0; t < 4; ++t)
#pragma unroll
      for (int r = 0; r < 4; ++r) {
        const float p = fexp2(sacc[t][r] - mrun[r]);
        ps[swz(((l >> 4) << 2) + r, t * 16 + arow)] = f2bf(p);
      }
    s16x8 pa[2];
#pragma unroll
    for (int kh = 0; kh < 2; ++kh)
      pa[kh] = *(const s16x8*)(ps + swz(arow, kh * 32 + kcol));
    // row-sum on the matrix pipe: lacc += P @ ones
    lacc = __builtin_amdgcn_mfma_f32_16x16x32_bf16(pa[0], ones, lacc, 0, 0, 0);
    lacc = __builtin_amdgcn_mfma_f32_16x16x32_bf16(pa[1], ones, lacc, 0, 0, 0);
    // PV from staged V^T
#pragma unroll
    for (int dg = 0; dg < 4; ++dg) {
      s16x8 v0 = *(const s16x8*)(Vb[cur] + swz(dg * 16 + arow, kcol));
      s16x8 v1 = *(const s16x8*)(Vb[cur] + swz(dg * 16 + arow, 32 + kcol));
      oacc[dg] = __builtin_amdgcn_mfma_f32_16x16x32_bf16(pa[0], v0, oacc[dg], 0, 0, 0);
      oacc[dg] = __builtin_amdgcn_mfma_f32_16x16x32_bf16(pa[1], v1, oacc[dg], 0, 0, 0);
    }
    __syncthreads();  // drains stage loads; next buffer ready, this buffer free
  }

  float inv[4];
#pragma unroll
  for (int r = 0; r < 4; ++r) inv[r] = 1.f / lacc[r];
#pragma unroll
  for (int dg = 0; dg < 4; ++dg)
#pragma unroll
    for (int r = 0; r < 4; ++r) {
      const int row = q0 + ((l >> 4) << 2) + r;
      O[(size_t)(b * 1024 + row) * 1024 + h * 64 + dg * 16 + arow] = f2bf(oacc[dg][r] * inv[r]);
    }
}

// ---------------- launcher ----------------
extern "C" void kernel_launch(void* const* d_in, const int* in_sizes, int n_in,
                              void* d_out, int out_size, void* d_ws, size_t ws_size,
                              hipStream_t stream) {
  const float* X = (const float*)d_in[0];
  const float* Wq = (const float*)d_in[1];
  const float* bq = (const float*)d_in[2];
  const float* Wk = (const float*)d_in[3];
  const float* bk = (const float*)d_in[4];
  const float* Wv = (const float*)d_in[5];
  const float* bv = (const float*)d_in[6];
  const float* pre_g = (const float*)d_in[7];
  const float* pre_b = (const float*)d_in[8];
  const float* post_g = (const float*)d_in[9];
  const float* post_b = (const float*)d_in[10];
  const float* W1 = (const float*)d_in[11];
  const float* b1 = (const float*)d_in[12];
  const float* ln1_g = (const float*)d_in[13];
  const float* ln1_b = (const float*)d_in[14];
  const float* W2 = (const float*)d_in[15];
  const float* b2 = (const float*)d_in[16];
  const float* ln2_g = (const float*)d_in[17];
  const float* ln2_b = (const float*)d_in[18];
  float* out = (float*)d_out;

  char* ws = (char*)d_ws;
  const size_t MB = (size_t)1 << 20;
  unsigned short* t_bf = (unsigned short*)(ws);             // [0,16)
  unsigned short* attn_o = (unsigned short*)(ws);           // [0,16) after t_bf dead
  unsigned short* mlp2 = (unsigned short*)(ws);             // [0,16) after attn_o dead
  unsigned short* qkv = (unsigned short*)(ws + 16 * MB);    // [16,64)
  unsigned short* mlp1 = (unsigned short*)(ws + 16 * MB);   // [16,48) after qkv dead
  unsigned short* Vt = (unsigned short*)(ws + 64 * MB);     // [64,80)
  unsigned short* h1 = (unsigned short*)(ws + 48 * MB);     // [48,80) after Vt dead
  unsigned short* t2 = (unsigned short*)(ws + 80 * MB);     // [80,96)
  unsigned short* Wqkvt = (unsigned short*)(ws + 96 * MB);  // [96,102)
  unsigned short* W1t = (unsigned short*)(ws + 102 * MB);   // [102,106)
  unsigned short* W2t = (unsigned short*)(ws + 106 * MB);   // [106,110)
  float* biasq = (float*)(ws + 110 * MB);

  // allow 144KB dynamic LDS for k_gemm2 (idempotent, same every call)
  hipFuncSetAttribute((const void*)k_gemm2,
                      hipFuncAttributeMaxDynamicSharedMemorySize, 3 * 49152);

  // weight prep (tiled transposes, coalesced both sides)
  k_tr<<<dim3(2, 32, 16), 256, 0, stream>>>(Wq, Wqkvt, 64, 1024, 65536, 65536);
  k_tr<<<dim3(2, 32, 16), 256, 0, stream>>>(Wk, Wqkvt + 1048576, 64, 1024, 65536, 65536);
  k_tr<<<dim3(2, 32, 16), 256, 0, stream>>>(Wv, Wqkvt + 2097152, 64, 1024, 65536, 65536);
  k_tr<<<dim3(64, 32, 1), 256, 0, stream>>>(W1, W1t, 2048, 1024, 0, 0);
  k_tr<<<dim3(32, 64, 1), 256, 0, stream>>>(W2, W2t, 1024, 2048, 0, 0);
  k_bias3<<<12, 256, 0, stream>>>(bq, bk, bv, biasq);

  // pre-LN
  k_pre_ln<<<8192, 256, 0, stream>>>(X, pre_g, pre_b, t_bf);
  // QKV projection (V columns written transposed into Vt): 768 blocks
  k_gemm2<<<dim3(24, 32), 512, 3 * 49152, stream>>>(t_bf, Wqkvt, biasq, qkv, 8192, 3072, 1024, 2048, Vt);
  // attention
  k_attn3<<<2048, 256, 0, stream>>>(qkv, Vt, attn_o);
  // residual + post-LN (X1 stored in d_out)
  k_res_ln<<<8192, 256, 0, stream>>>(X, attn_o, post_g, post_b, out, t2);
  // MLP1: 512 blocks
  k_gemm2<<<dim3(16, 32), 512, 3 * 49152, stream>>>(t2, W1t, b1, mlp1, 8192, 2048, 1024, 1 << 30, nullptr);
  k_ln_gelu<<<8192, 256, 0, stream>>>(mlp1, ln1_g, ln1_b, h1);
  // MLP2: 256 blocks
  k_gemm2<<<dim3(8, 32), 512, 3 * 49152, stream>>>(h1, W2t, b2, mlp2, 8192, 1024, 2048, 1 << 30, nullptr);
  // final: out = X1 + gelu(LN(mlp2))
  k_final<<<8192, 256, 0, stream>>>(mlp2, ln2_g, ln2_b, out);
}

// Round 7
// 468.279 us; speedup vs baseline: 1.4121x; 1.1085x over previous
//
#include <hip/hip_runtime.h>

typedef __attribute__((ext_vector_type(8))) short s16x8;
typedef __attribute__((ext_vector_type(8))) unsigned short u16x8;
typedef __attribute__((ext_vector_type(4))) unsigned short u16x4;
typedef __attribute__((ext_vector_type(4))) float f32x4;

__device__ __forceinline__ unsigned short f2bf(float f) {
  union { float f; unsigned int u; } v; v.f = f;
  unsigned int r = (v.u + 0x7FFFu + ((v.u >> 16) & 1u)) >> 16;
  return (unsigned short)r;
}
__device__ __forceinline__ float bf2f(unsigned short h) {
  union { unsigned int u; float f; } v; v.u = ((unsigned int)h) << 16;
  return v.f;
}
__device__ __forceinline__ float gelu(float x) {
  return 0.5f * x * (1.f + erff(x * 0.70710678118654752f));
}
__device__ __forceinline__ float fexp2(float x) {
  float r; asm("v_exp_f32 %0, %1" : "=v"(r) : "v"(x)); return r;
}

__device__ __forceinline__ void gld16(const void* g, void* l) {
  __builtin_amdgcn_global_load_lds(
      (const __attribute__((address_space(1))) unsigned int*)g,
      (__attribute__((address_space(3))) unsigned int*)l, 16, 0, 0);
}

__device__ __forceinline__ float blk_sum(float v, float* red, int tid, int nw) {
#pragma unroll
  for (int m = 32; m >= 1; m >>= 1) v += __shfl_xor(v, m);
  __syncthreads();
  if ((tid & 63) == 0) red[tid >> 6] = v;
  __syncthreads();
  float t = 0.f;
  for (int i = 0; i < nw; ++i) t += red[i];
  return t;
}

// ---------------- tiled transpose: fp32 [R][C] -> bf16 [C][R], batched ----------------
__global__ __launch_bounds__(256) void k_tr(
    const float* __restrict__ in, unsigned short* __restrict__ out,
    int inRS, int outRS, long inBS, long outBS) {
  __shared__ float t[32][33];
  const float* ip = in + (size_t)blockIdx.z * inBS;
  unsigned short* op = out + (size_t)blockIdx.z * outBS;
  const int r0 = blockIdx.y * 32, c0 = blockIdx.x * 32;
  const int tid = threadIdx.x;
  const int r = tid >> 3, c4 = (tid & 7) * 4;
  const f32x4 v = *(const f32x4*)(ip + (size_t)(r0 + r) * inRS + c0 + c4);
#pragma unroll
  for (int i = 0; i < 4; ++i) t[r][c4 + i] = v[i];
  __syncthreads();
  u16x4 o;
#pragma unroll
  for (int i = 0; i < 4; ++i) o[i] = f2bf(t[c4 + i][r]);
  *(u16x4*)(op + (size_t)(c0 + r) * outRS + r0 + c4) = o;
}

__global__ __launch_bounds__(256) void k_bias3(
    const float* __restrict__ a, const float* __restrict__ b,
    const float* __restrict__ c, float* __restrict__ o) {
  int i = blockIdx.x * 256 + threadIdx.x;
  if (i >= 3072) return;
  o[i] = (i < 1024) ? a[i] : ((i < 2048) ? b[i - 1024] : c[i - 2048]);
}

// ---------------- layernorm kernels ----------------
__global__ __launch_bounds__(256) void k_pre_ln(
    const float* __restrict__ X, const float* __restrict__ g,
    const float* __restrict__ bta, unsigned short* __restrict__ out) {
  __shared__ float red[4];
  const int row = blockIdx.x, tid = threadIdx.x;
  const f32x4 x = *(const f32x4*)(X + (size_t)row * 1024 + tid * 4);
  float s = x[0] + x[1] + x[2] + x[3];
  s = blk_sum(s, red, tid, 4);
  const float mean = s * (1.f / 1024.f);
  f32x4 d;
#pragma unroll
  for (int i = 0; i < 4; ++i) d[i] = x[i] - mean;
  float sq = d[0] * d[0] + d[1] * d[1] + d[2] * d[2] + d[3] * d[3];
  sq = blk_sum(sq, red, tid, 4);
  const float rstd = rsqrtf(sq * (1.f / 1024.f) + 1e-5f);
  const f32x4 gv = *(const f32x4*)(g + tid * 4);
  const f32x4 bv = *(const f32x4*)(bta + tid * 4);
  u16x4 o;
#pragma unroll
  for (int i = 0; i < 4; ++i) o[i] = f2bf(d[i] * rstd * gv[i] + bv[i]);
  *(u16x4*)(out + (size_t)row * 1024 + tid * 4) = o;
}

__global__ __launch_bounds__(256) void k_res_ln(
    const float* __restrict__ X, const unsigned short* __restrict__ attn,
    const float* __restrict__ g, const float* __restrict__ bta,
    float* __restrict__ X1, unsigned short* __restrict__ t2) {
  __shared__ float red[4];
  const int row = blockIdx.x, tid = threadIdx.x;
  const f32x4 x = *(const f32x4*)(X + (size_t)row * 1024 + tid * 4);
  const u16x4 a = *(const u16x4*)(attn + (size_t)row * 1024 + tid * 4);
  f32x4 x1;
#pragma unroll
  for (int i = 0; i < 4; ++i) x1[i] = x[i] + bf2f(a[i]);
  *(f32x4*)(X1 + (size_t)row * 1024 + tid * 4) = x1;
  float s = x1[0] + x1[1] + x1[2] + x1[3];
  s = blk_sum(s, red, tid, 4);
  const float mean = s * (1.f / 1024.f);
  f32x4 d;
#pragma unroll
  for (int i = 0; i < 4; ++i) d[i] = x1[i] - mean;
  float sq = d[0] * d[0] + d[1] * d[1] + d[2] * d[2] + d[3] * d[3];
  sq = blk_sum(sq, red, tid, 4);
  const float rstd = rsqrtf(sq * (1.f / 1024.f) + 1e-5f);
  const f32x4 gv = *(const f32x4*)(g + tid * 4);
  const f32x4 bv = *(const f32x4*)(bta + tid * 4);
  u16x4 o;
#pragma unroll
  for (int i = 0; i < 4; ++i) o[i] = f2bf(d[i] * rstd * gv[i] + bv[i]);
  *(u16x4*)(t2 + (size_t)row * 1024 + tid * 4) = o;
}

__global__ __launch_bounds__(256) void k_ln_gelu(
    const unsigned short* __restrict__ in, const float* __restrict__ g,
    const float* __restrict__ bta, unsigned short* __restrict__ out) {
  __shared__ float red[4];
  const int row = blockIdx.x, tid = threadIdx.x;
  const u16x8 iv = *(const u16x8*)(in + (size_t)row * 2048 + tid * 8);
  float v[8];
  float s = 0.f;
#pragma unroll
  for (int i = 0; i < 8; ++i) { v[i] = bf2f(iv[i]); s += v[i]; }
  s = blk_sum(s, red, tid, 4);
  const float mean = s * (1.f / 2048.f);
  float sq = 0.f;
#pragma unroll
  for (int i = 0; i < 8; ++i) { v[i] -= mean; sq += v[i] * v[i]; }
  sq = blk_sum(sq, red, tid, 4);
  const float rstd = rsqrtf(sq * (1.f / 2048.f) + 1e-5f);
  u16x8 o;
#pragma unroll
  for (int i = 0; i < 8; ++i) {
    float t = v[i] * rstd * g[tid * 8 + i] + bta[tid * 8 + i];
    o[i] = f2bf(gelu(t));
  }
  *(u16x8*)(out + (size_t)row * 2048 + tid * 8) = o;
}

__global__ __launch_bounds__(256) void k_final(
    const unsigned short* __restrict__ in, const float* __restrict__ g,
    const float* __restrict__ bta, float* __restrict__ io) {
  __shared__ float red[4];
  const int row = blockIdx.x, tid = threadIdx.x;
  const u16x4 iv = *(const u16x4*)(in + (size_t)row * 1024 + tid * 4);
  float v[4];
  float s = 0.f;
#pragma unroll
  for (int i = 0; i < 4; ++i) { v[i] = bf2f(iv[i]); s += v[i]; }
  s = blk_sum(s, red, tid, 4);
  const float mean = s * (1.f / 1024.f);
  float sq = 0.f;
#pragma unroll
  for (int i = 0; i < 4; ++i) { v[i] -= mean; sq += v[i] * v[i]; }
  sq = blk_sum(sq, red, tid, 4);
  const float rstd = rsqrtf(sq * (1.f / 1024.f) + 1e-5f);
  const f32x4 gv = *(const f32x4*)(g + tid * 4);
  const f32x4 bv = *(const f32x4*)(bta + tid * 4);
  f32x4 xi = *(const f32x4*)(io + (size_t)row * 1024 + tid * 4);
#pragma unroll
  for (int i = 0; i < 4; ++i)
    xi[i] += gelu(v[i] * rstd * gv[i] + bv[i]);
  *(f32x4*)(io + (size_t)row * 1024 + tid * 4) = xi;
}

// ---------------- GEMM v3: 128^2/BK=64, raw barriers + counted vmcnt (T3+T4) ----------
// C_bf16[M][N] = A_bf16[M][K] @ Bt_bf16[N][K] + bias; cols >= vsplit -> VtO transposed
// LDS: 2 buffers x (A 128x64 + B 128x64) = 64KB -> 2 blocks/CU.
__global__ __launch_bounds__(256) void k_gemm3(
    const unsigned short* __restrict__ A, const unsigned short* __restrict__ Bt,
    const float* __restrict__ bias, unsigned short* __restrict__ C,
    int M, int N, int K, int vsplit, unsigned short* __restrict__ VtO) {
  __shared__ __align__(16) unsigned short lds[2][16384];
  const int tid = threadIdx.x;
  const int w = tid >> 6, l = tid & 63;
  const int wm = w >> 1, wn = w & 1;
  const int gx = gridDim.x;
  int flat = blockIdx.y * gx + blockIdx.x;
  const int nwg = gx * gridDim.y;
  flat = (flat & 7) * (nwg >> 3) + (flat >> 3);  // XCD swizzle (all grids %8==0)
  const int m0 = (flat / gx) * 128, n0 = (flat % gx) * 128;

  const f32x4 z4 = {0.f, 0.f, 0.f, 0.f};
  f32x4 acc[4][4];
#pragma unroll
  for (int i = 0; i < 4; ++i)
#pragma unroll
    for (int j = 0; j < 4; ++j) acc[i][j] = z4;

  // stage one K-tile (A 16KB + B 16KB) = 8 gld16/thread; src col pre-swizzled (rule #21)
#define STG(t, d)                                                                   \
  {                                                                                 \
    const int kb = (t) * 64;                                                        \
    _Pragma("unroll") for (int i = 0; i < 4; ++i) {                                 \
      const int s = i * 256 + tid;                                                  \
      const int row = s >> 3, cs = s & 7;                                           \
      gld16(A + (size_t)(m0 + row) * K + kb + ((cs ^ (row & 7)) << 3),              \
            &lds[d][s * 8]);                                                        \
    }                                                                               \
    _Pragma("unroll") for (int i = 0; i < 4; ++i) {                                 \
      const int s = i * 256 + tid;                                                  \
      const int row = s >> 3, cs = s & 7;                                           \
      gld16(Bt + (size_t)(n0 + row) * K + kb + ((cs ^ (row & 7)) << 3),             \
            &lds[d][8192 + s * 8]);                                                 \
    }                                                                               \
  }

  const int nt = K >> 6;
  STG(0, 0);
  for (int t = 0; t < nt; ++t) {
    const int cur = t & 1;
    if (t + 1 < nt) {
      STG(t + 1, cur ^ 1);
      asm volatile("s_waitcnt vmcnt(8)" ::: "memory");  // tile t landed; t+1 in flight
    } else {
      asm volatile("s_waitcnt vmcnt(0)" ::: "memory");
    }
    __builtin_amdgcn_s_barrier();        // publish tile t to all waves
    asm volatile("" ::: "memory");
    __builtin_amdgcn_s_setprio(1);
#pragma unroll
    for (int ks = 0; ks < 2; ++ks) {
      const int g = ks * 4 + (l >> 4);
      s16x8 a[4], b[4];
#pragma unroll
      for (int m = 0; m < 4; ++m) {
        const int row = wm * 64 + m * 16 + (l & 15);
        a[m] = *(const s16x8*)&lds[cur][row * 64 + ((g ^ (row & 7)) << 3)];
      }
#pragma unroll
      for (int n = 0; n < 4; ++n) {
        const int row = wn * 64 + n * 16 + (l & 15);
        b[n] = *(const s16x8*)&lds[cur][8192 + row * 64 + ((g ^ (row & 7)) << 3)];
      }
#pragma unroll
      for (int m = 0; m < 4; ++m)
#pragma unroll
        for (int n = 0; n < 4; ++n)
          acc[m][n] = __builtin_amdgcn_mfma_f32_16x16x32_bf16(a[m], b[n], acc[m][n], 0, 0, 0);
    }
    __builtin_amdgcn_s_setprio(0);
    asm volatile("s_waitcnt lgkmcnt(0)" ::: "memory");  // my LDS reads delivered
    __builtin_amdgcn_s_barrier();        // release buf[cur] for overwrite at t+2
    asm volatile("" ::: "memory");
  }
#undef STG

  const int rbase = m0 + wm * 64 + ((l >> 4) << 2);
  const int cbase = n0 + wn * 64 + (l & 15);
#pragma unroll
  for (int n = 0; n < 4; ++n) {
    const int c = cbase + n * 16;
    const float bb = bias[c];
    if ((n0 + wn * 64 + n * 16) < vsplit) {
#pragma unroll
      for (int m = 0; m < 4; ++m)
#pragma unroll
        for (int r = 0; r < 4; ++r)
          C[(size_t)(rbase + m * 16 + r) * N + c] = f2bf(acc[m][n][r] + bb);
    } else {  // V region -> transposed per-head write
      const int cc = c - vsplit;
      const int hh = cc >> 6, dd = cc & 63;
#pragma unroll
      for (int m = 0; m < 4; ++m) {
        const int rr = rbase + m * 16;
        u16x4 o;
#pragma unroll
        for (int r = 0; r < 4; ++r) o[r] = f2bf(acc[m][n][r] + bb);
        *(u16x4*)(VtO + ((size_t)((rr >> 10) * 16 + hh)) * 65536 + dd * 1024 + (rr & 1023)) = o;
      }
    }
  }
}

// ---------------- attention: LDS-staged dbuf + scaled-Q + ones-trick + defer-max ----
__device__ __forceinline__ int swz(int r, int c) {
  return r * 64 + (c ^ ((r & 7) << 3));
}

__global__ __launch_bounds__(256) void k_attn3(
    const unsigned short* __restrict__ qkv, const unsigned short* __restrict__ Vt,
    unsigned short* __restrict__ O) {
  int bid = blockIdx.x;
  bid = (bid & 7) * 256 + (bid >> 3);  // XCD swizzle (2048 blocks)
  const int qt = bid & 15, h = (bid >> 4) & 15, b = bid >> 8;
  const int tid = threadIdx.x, w = tid >> 6, l = tid & 63;
  const int arow = l & 15, kcol = (l >> 4) * 8;

  __shared__ __align__(16) unsigned short Kb[2][64 * 64];
  __shared__ __align__(16) unsigned short Vb[2][64 * 64];
  __shared__ __align__(16) unsigned short Ps[4][16 * 64];
  unsigned short* ps = &Ps[w][0];

  const unsigned short* qb = qkv + (size_t)b * 1024 * 3072 + h * 64;
  const unsigned short* kb = qb + 1024;
  const unsigned short* vt = Vt + ((size_t)(b * 16 + h)) * 65536;
  const int q0 = qt * 64 + w * 16;

  const float c2 = 0.125f * 1.44269504088896f;  // exp2-domain scale, folded into Q

  s16x8 qa[2];
#pragma unroll
  for (int kh = 0; kh < 2; ++kh) {
    s16x8 q = *(const s16x8*)(qb + (size_t)(q0 + arow) * 3072 + kh * 32 + kcol);
#pragma unroll
    for (int j = 0; j < 8; ++j)
      q[j] = (short)f2bf(bf2f((unsigned short)q[j]) * c2);
    qa[kh] = q;
  }
  s16x8 ones;
#pragma unroll
  for (int j = 0; j < 8; ++j) ones[j] = (short)0x3F80;  // bf16 1.0

  const int srow = tid >> 3;
  const int sce = 8 * ((tid & 7) ^ (srow & 7));
  const int sdst = srow * 64 + (tid & 7) * 8;

#pragma unroll
  for (int i = 0; i < 2; ++i) {
    gld16(kb + (size_t)(i * 32 + srow) * 3072 + sce, Kb[0] + i * 2048 + sdst);
    gld16(vt + (size_t)(i * 32 + srow) * 1024 + sce, Vb[0] + i * 2048 + sdst);
  }
  __syncthreads();

  const f32x4 z4 = {0.f, 0.f, 0.f, 0.f};
  f32x4 oacc[4];
#pragma unroll
  for (int i = 0; i < 4; ++i) oacc[i] = z4;
  f32x4 lacc = z4;
  float mrun[4];
#pragma unroll
  for (int r = 0; r < 4; ++r) mrun[r] = -1e30f;

  for (int kc = 0; kc < 16; ++kc) {
    const int cur = kc & 1;
    if (kc < 15) {
      const int key1 = (kc + 1) * 64;
#pragma unroll
      for (int i = 0; i < 2; ++i) {
        gld16(kb + (size_t)(key1 + i * 32 + srow) * 3072 + sce, Kb[cur ^ 1] + i * 2048 + sdst);
        gld16(vt + (size_t)(i * 32 + srow) * 1024 + key1 + sce, Vb[cur ^ 1] + i * 2048 + sdst);
      }
    }
    f32x4 sacc[4];
#pragma unroll
    for (int t = 0; t < 4; ++t) {
      s16x8 k0 = *(const s16x8*)(Kb[cur] + swz(t * 16 + arow, kcol));
      s16x8 k1 = *(const s16x8*)(Kb[cur] + swz(t * 16 + arow, 32 + kcol));
      f32x4 s = z4;
      s = __builtin_amdgcn_mfma_f32_16x16x32_bf16(qa[0], k0, s, 0, 0, 0);
      s = __builtin_amdgcn_mfma_f32_16x16x32_bf16(qa[1], k1, s, 0, 0, 0);
      sacc[t] = s;
    }
    float rmax[4];
#pragma unroll
    for (int r = 0; r < 4; ++r) {
      float m = fmaxf(fmaxf(sacc[0][r], sacc[1][r]), fmaxf(sacc[2][r], sacc[3][r]));
#pragma unroll
      for (int msk = 8; msk >= 1; msk >>= 1) m = fmaxf(m, __shfl_xor(m, msk));
      rmax[r] = m;
    }
    const float need = fmaxf(fmaxf(rmax[0] - mrun[0], rmax[1] - mrun[1]),
                             fmaxf(rmax[2] - mrun[2], rmax[3] - mrun[3]));
    if (!__all(need <= 8.f)) {
      float sc[4];
#pragma unroll
      for (int r = 0; r < 4; ++r) {
        const float nm = fmaxf(mrun[r], rmax[r]);
        sc[r] = fexp2(mrun[r] - nm);
        mrun[r] = nm;
      }
#pragma unroll
      for (int r = 0; r < 4; ++r) {
        lacc[r] *= sc[r];
#pragma unroll
        for (int dg = 0; dg < 4; ++dg) oacc[dg][r] *= sc[r];
      }
    }
#pragma unroll
    for (int t = 0; t < 4; ++t)
#pragma unroll
      for (int r = 0; r < 4; ++r) {
        const float p = fexp2(sacc[t][r] - mrun[r]);
        ps[swz(((l >> 4) << 2) + r, t * 16 + arow)] = f2bf(p);
      }
    s16x8 pa[2];
#pragma unroll
    for (int kh = 0; kh < 2; ++kh)
      pa[kh] = *(const s16x8*)(ps + swz(arow, kh * 32 + kcol));
    lacc = __builtin_amdgcn_mfma_f32_16x16x32_bf16(pa[0], ones, lacc, 0, 0, 0);
    lacc = __builtin_amdgcn_mfma_f32_16x16x32_bf16(pa[1], ones, lacc, 0, 0, 0);
#pragma unroll
    for (int dg = 0; dg < 4; ++dg) {
      s16x8 v0 = *(const s16x8*)(Vb[cur] + swz(dg * 16 + arow, kcol));
      s16x8 v1 = *(const s16x8*)(Vb[cur] + swz(dg * 16 + arow, 32 + kcol));
      oacc[dg] = __builtin_amdgcn_mfma_f32_16x16x32_bf16(pa[0], v0, oacc[dg], 0, 0, 0);
      oacc[dg] = __builtin_amdgcn_mfma_f32_16x16x32_bf16(pa[1], v1, oacc[dg], 0, 0, 0);
    }
    __syncthreads();
  }

  float inv[4];
#pragma unroll
  for (int r = 0; r < 4; ++r) inv[r] = 1.f / lacc[r];
#pragma unroll
  for (int dg = 0; dg < 4; ++dg)
#pragma unroll
    for (int r = 0; r < 4; ++r) {
      const int row = q0 + ((l >> 4) << 2) + r;
      O[(size_t)(b * 1024 + row) * 1024 + h * 64 + dg * 16 + arow] = f2bf(oacc[dg][r] * inv[r]);
    }
}

// ---------------- launcher ----------------
extern "C" void kernel_launch(void* const* d_in, const int* in_sizes, int n_in,
                              void* d_out, int out_size, void* d_ws, size_t ws_size,
                              hipStream_t stream) {
  const float* X = (const float*)d_in[0];
  const float* Wq = (const float*)d_in[1];
  const float* bq = (const float*)d_in[2];
  const float* Wk = (const float*)d_in[3];
  const float* bk = (const float*)d_in[4];
  const float* Wv = (const float*)d_in[5];
  const float* bv = (const float*)d_in[6];
  const float* pre_g = (const float*)d_in[7];
  const float* pre_b = (const float*)d_in[8];
  const float* post_g = (const float*)d_in[9];
  const float* post_b = (const float*)d_in[10];
  const float* W1 = (const float*)d_in[11];
  const float* b1 = (const float*)d_in[12];
  const float* ln1_g = (const float*)d_in[13];
  const float* ln1_b = (const float*)d_in[14];
  const float* W2 = (const float*)d_in[15];
  const float* b2 = (const float*)d_in[16];
  const float* ln2_g = (const float*)d_in[17];
  const float* ln2_b = (const float*)d_in[18];
  float* out = (float*)d_out;

  char* ws = (char*)d_ws;
  const size_t MB = (size_t)1 << 20;
  unsigned short* t_bf = (unsigned short*)(ws);             // [0,16)
  unsigned short* attn_o = (unsigned short*)(ws);           // [0,16) after t_bf dead
  unsigned short* mlp2 = (unsigned short*)(ws);             // [0,16) after attn_o dead
  unsigned short* qkv = (unsigned short*)(ws + 16 * MB);    // [16,64)
  unsigned short* mlp1 = (unsigned short*)(ws + 16 * MB);   // [16,48) after qkv dead
  unsigned short* Vt = (unsigned short*)(ws + 64 * MB);     // [64,80)
  unsigned short* h1 = (unsigned short*)(ws + 48 * MB);     // [48,80) after Vt dead
  unsigned short* t2 = (unsigned short*)(ws + 80 * MB);     // [80,96)
  unsigned short* Wqkvt = (unsigned short*)(ws + 96 * MB);  // [96,102)
  unsigned short* W1t = (unsigned short*)(ws + 102 * MB);   // [102,106)
  unsigned short* W2t = (unsigned short*)(ws + 106 * MB);   // [106,110)
  float* biasq = (float*)(ws + 110 * MB);

  // weight prep (tiled transposes, coalesced both sides)
  k_tr<<<dim3(2, 32, 16), 256, 0, stream>>>(Wq, Wqkvt, 64, 1024, 65536, 65536);
  k_tr<<<dim3(2, 32, 16), 256, 0, stream>>>(Wk, Wqkvt + 1048576, 64, 1024, 65536, 65536);
  k_tr<<<dim3(2, 32, 16), 256, 0, stream>>>(Wv, Wqkvt + 2097152, 64, 1024, 65536, 65536);
  k_tr<<<dim3(64, 32, 1), 256, 0, stream>>>(W1, W1t, 2048, 1024, 0, 0);
  k_tr<<<dim3(32, 64, 1), 256, 0, stream>>>(W2, W2t, 1024, 2048, 0, 0);
  k_bias3<<<12, 256, 0, stream>>>(bq, bk, bv, biasq);

  // pre-LN
  k_pre_ln<<<8192, 256, 0, stream>>>(X, pre_g, pre_b, t_bf);
  // QKV projection (V columns written transposed into Vt): 1536 blocks
  k_gemm3<<<dim3(24, 64), 256, 0, stream>>>(t_bf, Wqkvt, biasq, qkv, 8192, 3072, 1024, 2048, Vt);
  // attention
  k_attn3<<<2048, 256, 0, stream>>>(qkv, Vt, attn_o);
  // residual + post-LN (X1 stored in d_out)
  k_res_ln<<<8192, 256, 0, stream>>>(X, attn_o, post_g, post_b, out, t2);
  // MLP1: 1024 blocks
  k_gemm3<<<dim3(16, 64), 256, 0, stream>>>(t2, W1t, b1, mlp1, 8192, 2048, 1024, 1 << 30, nullptr);
  k_ln_gelu<<<8192, 256, 0, stream>>>(mlp1, ln1_g, ln1_b, h1);
  // MLP2: 512 blocks
  k_gemm3<<<dim3(8, 64), 256, 0, stream>>>(h1, W2t, b2, mlp2, 8192, 1024, 2048, 1 << 30, nullptr);
  // final: out = X1 + gelu(LN(mlp2))
  k_final<<<8192, 256, 0, stream>>>(mlp2, ln2_g, ln2_b, out);
}

// Round 8
// 446.355 us; speedup vs baseline: 1.4815x; 1.0491x over previous
//
#include <hip/hip_runtime.h>

typedef __attribute__((ext_vector_type(8))) short s16x8;
typedef __attribute__((ext_vector_type(8))) unsigned short u16x8;
typedef __attribute__((ext_vector_type(4))) unsigned short u16x4;
typedef __attribute__((ext_vector_type(4))) float f32x4;
typedef __attribute__((ext_vector_type(2))) unsigned int u32x2;

__device__ __forceinline__ unsigned short f2bf(float f) {
  union { float f; unsigned int u; } v; v.f = f;
  unsigned int r = (v.u + 0x7FFFu + ((v.u >> 16) & 1u)) >> 16;
  return (unsigned short)r;
}
__device__ __forceinline__ float bf2f(unsigned short h) {
  union { unsigned int u; float f; } v; v.u = ((unsigned int)h) << 16;
  return v.f;
}
__device__ __forceinline__ float gelu(float x) {
  return 0.5f * x * (1.f + erff(x * 0.70710678118654752f));
}
__device__ __forceinline__ float fexp2(float x) {
  float r; asm("v_exp_f32 %0, %1" : "=v"(r) : "v"(x)); return r;
}
__device__ __forceinline__ unsigned int cvtpk(float lo, float hi) {
  unsigned int r;
  asm("v_cvt_pk_bf16_f32 %0, %1, %2" : "=v"(r) : "v"(lo), "v"(hi));
  return r;
}

__device__ __forceinline__ void gld16(const void* g, void* l) {
  __builtin_amdgcn_global_load_lds(
      (const __attribute__((address_space(1))) unsigned int*)g,
      (__attribute__((address_space(3))) unsigned int*)l, 16, 0, 0);
}

__device__ __forceinline__ float blk_sum(float v, float* red, int tid, int nw) {
#pragma unroll
  for (int m = 32; m >= 1; m >>= 1) v += __shfl_xor(v, m);
  __syncthreads();
  if ((tid & 63) == 0) red[tid >> 6] = v;
  __syncthreads();
  float t = 0.f;
  for (int i = 0; i < nw; ++i) t += red[i];
  return t;
}

// ---------------- tiled transpose: fp32 [R][C] -> bf16 [C][R], batched ----------------
__global__ __launch_bounds__(256) void k_tr(
    const float* __restrict__ in, unsigned short* __restrict__ out,
    int inRS, int outRS, long inBS, long outBS) {
  __shared__ float t[32][33];
  const float* ip = in + (size_t)blockIdx.z * inBS;
  unsigned short* op = out + (size_t)blockIdx.z * outBS;
  const int r0 = blockIdx.y * 32, c0 = blockIdx.x * 32;
  const int tid = threadIdx.x;
  const int r = tid >> 3, c4 = (tid & 7) * 4;
  const f32x4 v = *(const f32x4*)(ip + (size_t)(r0 + r) * inRS + c0 + c4);
#pragma unroll
  for (int i = 0; i < 4; ++i) t[r][c4 + i] = v[i];
  __syncthreads();
  u16x4 o;
#pragma unroll
  for (int i = 0; i < 4; ++i) o[i] = f2bf(t[c4 + i][r]);
  *(u16x4*)(op + (size_t)(c0 + r) * outRS + r0 + c4) = o;
}

__global__ __launch_bounds__(256) void k_bias3(
    const float* __restrict__ a, const float* __restrict__ b,
    const float* __restrict__ c, float* __restrict__ o) {
  int i = blockIdx.x * 256 + threadIdx.x;
  if (i >= 3072) return;
  o[i] = (i < 1024) ? a[i] : ((i < 2048) ? b[i - 1024] : c[i - 2048]);
}

// ---------------- layernorm kernels ----------------
__global__ __launch_bounds__(256) void k_pre_ln(
    const float* __restrict__ X, const float* __restrict__ g,
    const float* __restrict__ bta, unsigned short* __restrict__ out) {
  __shared__ float red[4];
  const int row = blockIdx.x, tid = threadIdx.x;
  const f32x4 x = *(const f32x4*)(X + (size_t)row * 1024 + tid * 4);
  float s = x[0] + x[1] + x[2] + x[3];
  s = blk_sum(s, red, tid, 4);
  const float mean = s * (1.f / 1024.f);
  f32x4 d;
#pragma unroll
  for (int i = 0; i < 4; ++i) d[i] = x[i] - mean;
  float sq = d[0] * d[0] + d[1] * d[1] + d[2] * d[2] + d[3] * d[3];
  sq = blk_sum(sq, red, tid, 4);
  const float rstd = rsqrtf(sq * (1.f / 1024.f) + 1e-5f);
  const f32x4 gv = *(const f32x4*)(g + tid * 4);
  const f32x4 bv = *(const f32x4*)(bta + tid * 4);
  u16x4 o;
#pragma unroll
  for (int i = 0; i < 4; ++i) o[i] = f2bf(d[i] * rstd * gv[i] + bv[i]);
  *(u16x4*)(out + (size_t)row * 1024 + tid * 4) = o;
}

__global__ __launch_bounds__(256) void k_res_ln(
    const float* __restrict__ X, const unsigned short* __restrict__ attn,
    const float* __restrict__ g, const float* __restrict__ bta,
    float* __restrict__ X1, unsigned short* __restrict__ t2) {
  __shared__ float red[4];
  const int row = blockIdx.x, tid = threadIdx.x;
  const f32x4 x = *(const f32x4*)(X + (size_t)row * 1024 + tid * 4);
  const u16x4 a = *(const u16x4*)(attn + (size_t)row * 1024 + tid * 4);
  f32x4 x1;
#pragma unroll
  for (int i = 0; i < 4; ++i) x1[i] = x[i] + bf2f(a[i]);
  *(f32x4*)(X1 + (size_t)row * 1024 + tid * 4) = x1;
  float s = x1[0] + x1[1] + x1[2] + x1[3];
  s = blk_sum(s, red, tid, 4);
  const float mean = s * (1.f / 1024.f);
  f32x4 d;
#pragma unroll
  for (int i = 0; i < 4; ++i) d[i] = x1[i] - mean;
  float sq = d[0] * d[0] + d[1] * d[1] + d[2] * d[2] + d[3] * d[3];
  sq = blk_sum(sq, red, tid, 4);
  const float rstd = rsqrtf(sq * (1.f / 1024.f) + 1e-5f);
  const f32x4 gv = *(const f32x4*)(g + tid * 4);
  const f32x4 bv = *(const f32x4*)(bta + tid * 4);
  u16x4 o;
#pragma unroll
  for (int i = 0; i < 4; ++i) o[i] = f2bf(d[i] * rstd * gv[i] + bv[i]);
  *(u16x4*)(t2 + (size_t)row * 1024 + tid * 4) = o;
}

__global__ __launch_bounds__(256) void k_ln_gelu(
    const unsigned short* __restrict__ in, const float* __restrict__ g,
    const float* __restrict__ bta, unsigned short* __restrict__ out) {
  __shared__ float red[4];
  const int row = blockIdx.x, tid = threadIdx.x;
  const u16x8 iv = *(const u16x8*)(in + (size_t)row * 2048 + tid * 8);
  float v[8];
  float s = 0.f;
#pragma unroll
  for (int i = 0; i < 8; ++i) { v[i] = bf2f(iv[i]); s += v[i]; }
  s = blk_sum(s, red, tid, 4);
  const float mean = s * (1.f / 2048.f);
  float sq = 0.f;
#pragma unroll
  for (int i = 0; i < 8; ++i) { v[i] -= mean; sq += v[i] * v[i]; }
  sq = blk_sum(sq, red, tid, 4);
  const float rstd = rsqrtf(sq * (1.f / 2048.f) + 1e-5f);
  u16x8 o;
#pragma unroll
  for (int i = 0; i < 8; ++i) {
    float t = v[i] * rstd * g[tid * 8 + i] + bta[tid * 8 + i];
    o[i] = f2bf(gelu(t));
  }
  *(u16x8*)(out + (size_t)row * 2048 + tid * 8) = o;
}

__global__ __launch_bounds__(256) void k_final(
    const unsigned short* __restrict__ in, const float* __restrict__ g,
    const float* __restrict__ bta, float* __restrict__ io) {
  __shared__ float red[4];
  const int row = blockIdx.x, tid = threadIdx.x;
  const u16x4 iv = *(const u16x4*)(in + (size_t)row * 1024 + tid * 4);
  float v[4];
  float s = 0.f;
#pragma unroll
  for (int i = 0; i < 4; ++i) { v[i] = bf2f(iv[i]); s += v[i]; }
  s = blk_sum(s, red, tid, 4);
  const float mean = s * (1.f / 1024.f);
  float sq = 0.f;
#pragma unroll
  for (int i = 0; i < 4; ++i) { v[i] -= mean; sq += v[i] * v[i]; }
  sq = blk_sum(sq, red, tid, 4);
  const float rstd = rsqrtf(sq * (1.f / 1024.f) + 1e-5f);
  const f32x4 gv = *(const f32x4*)(g + tid * 4);
  const f32x4 bv = *(const f32x4*)(bta + tid * 4);
  f32x4 xi = *(const f32x4*)(io + (size_t)row * 1024 + tid * 4);
#pragma unroll
  for (int i = 0; i < 4; ++i)
    xi[i] += gelu(v[i] * rstd * gv[i] + bv[i]);
  *(f32x4*)(io + (size_t)row * 1024 + tid * 4) = xi;
}

// ---------------- GEMM v3: 128^2/BK=64, raw barriers + counted vmcnt (T3+T4) ----------
__global__ __launch_bounds__(256) void k_gemm3(
    const unsigned short* __restrict__ A, const unsigned short* __restrict__ Bt,
    const float* __restrict__ bias, unsigned short* __restrict__ C,
    int M, int N, int K, int vsplit, unsigned short* __restrict__ VtO) {
  __shared__ __align__(16) unsigned short lds[2][16384];
  const int tid = threadIdx.x;
  const int w = tid >> 6, l = tid & 63;
  const int wm = w >> 1, wn = w & 1;
  const int gx = gridDim.x;
  int flat = blockIdx.y * gx + blockIdx.x;
  const int nwg = gx * gridDim.y;
  flat = (flat & 7) * (nwg >> 3) + (flat >> 3);  // XCD swizzle (all grids %8==0)
  const int m0 = (flat / gx) * 128, n0 = (flat % gx) * 128;

  const f32x4 z4 = {0.f, 0.f, 0.f, 0.f};
  f32x4 acc[4][4];
#pragma unroll
  for (int i = 0; i < 4; ++i)
#pragma unroll
    for (int j = 0; j < 4; ++j) acc[i][j] = z4;

#define STG(t, d)                                                                   \
  {                                                                                 \
    const int kb = (t) * 64;                                                        \
    _Pragma("unroll") for (int i = 0; i < 4; ++i) {                                 \
      const int s = i * 256 + tid;                                                  \
      const int row = s >> 3, cs = s & 7;                                           \
      gld16(A + (size_t)(m0 + row) * K + kb + ((cs ^ (row & 7)) << 3),              \
            &lds[d][s * 8]);                                                        \
    }                                                                               \
    _Pragma("unroll") for (int i = 0; i < 4; ++i) {                                 \
      const int s = i * 256 + tid;                                                  \
      const int row = s >> 3, cs = s & 7;                                           \
      gld16(Bt + (size_t)(n0 + row) * K + kb + ((cs ^ (row & 7)) << 3),             \
            &lds[d][8192 + s * 8]);                                                 \
    }                                                                               \
  }

  const int nt = K >> 6;
  STG(0, 0);
  for (int t = 0; t < nt; ++t) {
    const int cur = t & 1;
    if (t + 1 < nt) {
      STG(t + 1, cur ^ 1);
      asm volatile("s_waitcnt vmcnt(8)" ::: "memory");
    } else {
      asm volatile("s_waitcnt vmcnt(0)" ::: "memory");
    }
    __builtin_amdgcn_s_barrier();
    asm volatile("" ::: "memory");
    __builtin_amdgcn_s_setprio(1);
#pragma unroll
    for (int ks = 0; ks < 2; ++ks) {
      const int g = ks * 4 + (l >> 4);
      s16x8 a[4], b[4];
#pragma unroll
      for (int m = 0; m < 4; ++m) {
        const int row = wm * 64 + m * 16 + (l & 15);
        a[m] = *(const s16x8*)&lds[cur][row * 64 + ((g ^ (row & 7)) << 3)];
      }
#pragma unroll
      for (int n = 0; n < 4; ++n) {
        const int row = wn * 64 + n * 16 + (l & 15);
        b[n] = *(const s16x8*)&lds[cur][8192 + row * 64 + ((g ^ (row & 7)) << 3)];
      }
#pragma unroll
      for (int m = 0; m < 4; ++m)
#pragma unroll
        for (int n = 0; n < 4; ++n)
          acc[m][n] = __builtin_amdgcn_mfma_f32_16x16x32_bf16(a[m], b[n], acc[m][n], 0, 0, 0);
    }
    __builtin_amdgcn_s_setprio(0);
    asm volatile("s_waitcnt lgkmcnt(0)" ::: "memory");
    __builtin_amdgcn_s_barrier();
    asm volatile("" ::: "memory");
  }
#undef STG

  const int rbase = m0 + wm * 64 + ((l >> 4) << 2);
  const int cbase = n0 + wn * 64 + (l & 15);
#pragma unroll
  for (int n = 0; n < 4; ++n) {
    const int c = cbase + n * 16;
    const float bb = bias[c];
    if ((n0 + wn * 64 + n * 16) < vsplit) {
#pragma unroll
      for (int m = 0; m < 4; ++m)
#pragma unroll
        for (int r = 0; r < 4; ++r)
          C[(size_t)(rbase + m * 16 + r) * N + c] = f2bf(acc[m][n][r] + bb);
    } else {  // V region -> transposed per-head write
      const int cc = c - vsplit;
      const int hh = cc >> 6, dd = cc & 63;
#pragma unroll
      for (int m = 0; m < 4; ++m) {
        const int rr = rbase + m * 16;
        u16x4 o;
#pragma unroll
        for (int r = 0; r < 4; ++r) o[r] = f2bf(acc[m][n][r] + bb);
        *(u16x4*)(VtO + ((size_t)((rr >> 10) * 16 + hh)) * 65536 + dd * 1024 + (rr & 1023)) = o;
      }
    }
  }
}

// ---------------- attention v4: swapped QK^T (S^T = K·Q^T), lane-local softmax ------
__device__ __forceinline__ int swz(int r, int c) {
  return r * 64 + (c ^ ((r & 7) << 3));
}

__global__ __launch_bounds__(256) void k_attn4(
    const unsigned short* __restrict__ qkv, const unsigned short* __restrict__ Vt,
    unsigned short* __restrict__ O) {
  int bid = blockIdx.x;
  bid = (bid & 7) * 256 + (bid >> 3);  // XCD swizzle (2048 blocks)
  const int qt = bid & 15, h = (bid >> 4) & 15, b = bid >> 8;
  const int tid = threadIdx.x, w = tid >> 6, l = tid & 63;
  const int arow = l & 15, g = l >> 4, kcol = g * 8;

  __shared__ __align__(16) unsigned short Kb[2][64 * 64];
  __shared__ __align__(16) unsigned short Vb[2][64 * 64];
  __shared__ __align__(16) unsigned short Ps[4][16 * 64];
  unsigned short* ps = &Ps[w][0];

  const unsigned short* qb = qkv + (size_t)b * 1024 * 3072 + h * 64;
  const unsigned short* kb = qb + 1024;
  const unsigned short* vt = Vt + ((size_t)(b * 16 + h)) * 65536;
  const int q0 = qt * 64 + w * 16;

  const float c2 = 0.125f * 1.44269504088896f;  // exp2-domain scale folded into Q

  // Q as B-operand fragments (lane: q-row = arow, k-slice = kcol), pre-scaled
  s16x8 qa[2];
#pragma unroll
  for (int kh = 0; kh < 2; ++kh) {
    s16x8 q = *(const s16x8*)(qb + (size_t)(q0 + arow) * 3072 + kh * 32 + kcol);
#pragma unroll
    for (int j = 0; j < 8; ++j)
      q[j] = (short)f2bf(bf2f((unsigned short)q[j]) * c2);
    qa[kh] = q;
  }
  s16x8 ones;
#pragma unroll
  for (int j = 0; j < 8; ++j) ones[j] = (short)0x3F80;  // bf16 1.0

  const int srow = tid >> 3;
  const int sce = 8 * ((tid & 7) ^ (srow & 7));
  const int sdst = srow * 64 + (tid & 7) * 8;

#pragma unroll
  for (int i = 0; i < 2; ++i) {
    gld16(kb + (size_t)(i * 32 + srow) * 3072 + sce, Kb[0] + i * 2048 + sdst);
    gld16(vt + (size_t)(i * 32 + srow) * 1024 + sce, Vb[0] + i * 2048 + sdst);
  }
  __syncthreads();

  const f32x4 z4 = {0.f, 0.f, 0.f, 0.f};
  f32x4 oacc[4];  // O^T: oacc[dg][r] = O^T[dg*16 + g*4 + r][q=arow]
#pragma unroll
  for (int i = 0; i < 4; ++i) oacc[i] = z4;
  f32x4 lacc = z4;      // row-sum of P for this lane's q (all 4 regs equal)
  float mrun = -1e30f;  // running max for this lane's q

  for (int kc = 0; kc < 16; ++kc) {
    const int cur = kc & 1;
    if (kc < 15) {
      const int key1 = (kc + 1) * 64;
#pragma unroll
      for (int i = 0; i < 2; ++i) {
        gld16(kb + (size_t)(key1 + i * 32 + srow) * 3072 + sce, Kb[cur ^ 1] + i * 2048 + sdst);
        gld16(vt + (size_t)(i * 32 + srow) * 1024 + key1 + sce, Vb[cur ^ 1] + i * 2048 + sdst);
      }
    }
    // S^T tiles: st[t][r] = S[key = kc*64 + t*16 + g*4 + r][q]
    f32x4 st[4];
#pragma unroll
    for (int t = 0; t < 4; ++t) {
      s16x8 k0 = *(const s16x8*)(Kb[cur] + swz(t * 16 + arow, kcol));
      s16x8 k1 = *(const s16x8*)(Kb[cur] + swz(t * 16 + arow, 32 + kcol));
      f32x4 s = z4;
      s = __builtin_amdgcn_mfma_f32_16x16x32_bf16(k0, qa[0], s, 0, 0, 0);
      s = __builtin_amdgcn_mfma_f32_16x16x32_bf16(k1, qa[1], s, 0, 0, 0);
      st[t] = s;
    }
    // in-lane max over 16 keys + 2-level cross-g reduce
    float mx = fmaxf(fmaxf(st[0][0], st[0][1]), fmaxf(st[0][2], st[0][3]));
#pragma unroll
    for (int t = 1; t < 4; ++t)
      mx = fmaxf(mx, fmaxf(fmaxf(st[t][0], st[t][1]), fmaxf(st[t][2], st[t][3])));
    mx = fmaxf(mx, __shfl_xor(mx, 16));
    mx = fmaxf(mx, __shfl_xor(mx, 32));
    // defer-max (T13)
    if (!__all(mx - mrun <= 8.f)) {
      const float nm = fmaxf(mrun, mx);
      const float sc = fexp2(mrun - nm);
      mrun = nm;
#pragma unroll
      for (int r = 0; r < 4; ++r) lacc[r] *= sc;
#pragma unroll
      for (int dg = 0; dg < 4; ++dg)
#pragma unroll
        for (int r = 0; r < 4; ++r) oacc[dg][r] *= sc;
    }
    // P = exp2(S - m): pack 4 consecutive keys per b64 write (row q, cols t*16+4g)
#pragma unroll
    for (int t = 0; t < 4; ++t) {
      const unsigned int d0 = cvtpk(fexp2(st[t][0] - mrun), fexp2(st[t][1] - mrun));
      const unsigned int d1 = cvtpk(fexp2(st[t][2] - mrun), fexp2(st[t][3] - mrun));
      u32x2 u = {d0, d1};
      *(u32x2*)(ps + swz(arow, t * 16 + 4 * g)) = u;
    }
    // B-operand P fragments (row q = arow, keys kh*32 + g*8)
    s16x8 pa[2];
#pragma unroll
    for (int kh = 0; kh < 2; ++kh)
      pa[kh] = *(const s16x8*)(ps + swz(arow, kh * 32 + kcol));
    // row-sum on matrix pipe: D[i][q] = sum_k P[q][k]
    lacc = __builtin_amdgcn_mfma_f32_16x16x32_bf16(ones, pa[0], lacc, 0, 0, 0);
    lacc = __builtin_amdgcn_mfma_f32_16x16x32_bf16(ones, pa[1], lacc, 0, 0, 0);
    // PV: O^T[d][q] += V^T-frag (A) x P (B)
#pragma unroll
    for (int dg = 0; dg < 4; ++dg) {
      s16x8 v0 = *(const s16x8*)(Vb[cur] + swz(dg * 16 + arow, kcol));
      s16x8 v1 = *(const s16x8*)(Vb[cur] + swz(dg * 16 + arow, 32 + kcol));
      oacc[dg] = __builtin_amdgcn_mfma_f32_16x16x32_bf16(v0, pa[0], oacc[dg], 0, 0, 0);
      oacc[dg] = __builtin_amdgcn_mfma_f32_16x16x32_bf16(v1, pa[1], oacc[dg], 0, 0, 0);
    }
    __syncthreads();  // drains stage loads; next buffer ready, this buffer free
  }

  // epilogue: O^T -> Ps (row q, cols d) -> coalesced global store
  const float inv = 1.f / lacc[0];
#pragma unroll
  for (int dg = 0; dg < 4; ++dg) {
    const unsigned int d0 = cvtpk(oacc[dg][0] * inv, oacc[dg][1] * inv);
    const unsigned int d1 = cvtpk(oacc[dg][2] * inv, oacc[dg][3] * inv);
    u32x2 u = {d0, d1};
    *(u32x2*)(ps + swz(arow, dg * 16 + 4 * g)) = u;
  }
  const int rq = l >> 2, dc = (l & 3) * 16;
  u16x8 o0 = *(const u16x8*)(ps + swz(rq, dc));
  u16x8 o1 = *(const u16x8*)(ps + swz(rq, dc + 8));
  unsigned short* orow = O + (size_t)(b * 1024 + q0 + rq) * 1024 + h * 64 + dc;
  *(u16x8*)(orow) = o0;
  *(u16x8*)(orow + 8) = o1;
}

// ---------------- launcher ----------------
extern "C" void kernel_launch(void* const* d_in, const int* in_sizes, int n_in,
                              void* d_out, int out_size, void* d_ws, size_t ws_size,
                              hipStream_t stream) {
  const float* X = (const float*)d_in[0];
  const float* Wq = (const float*)d_in[1];
  const float* bq = (const float*)d_in[2];
  const float* Wk = (const float*)d_in[3];
  const float* bk = (const float*)d_in[4];
  const float* Wv = (const float*)d_in[5];
  const float* bv = (const float*)d_in[6];
  const float* pre_g = (const float*)d_in[7];
  const float* pre_b = (const float*)d_in[8];
  const float* post_g = (const float*)d_in[9];
  const float* post_b = (const float*)d_in[10];
  const float* W1 = (const float*)d_in[11];
  const float* b1 = (const float*)d_in[12];
  const float* ln1_g = (const float*)d_in[13];
  const float* ln1_b = (const float*)d_in[14];
  const float* W2 = (const float*)d_in[15];
  const float* b2 = (const float*)d_in[16];
  const float* ln2_g = (const float*)d_in[17];
  const float* ln2_b = (const float*)d_in[18];
  float* out = (float*)d_out;

  char* ws = (char*)d_ws;
  const size_t MB = (size_t)1 << 20;
  unsigned short* t_bf = (unsigned short*)(ws);             // [0,16)
  unsigned short* attn_o = (unsigned short*)(ws);           // [0,16) after t_bf dead
  unsigned short* mlp2 = (unsigned short*)(ws);             // [0,16) after attn_o dead
  unsigned short* qkv = (unsigned short*)(ws + 16 * MB);    // [16,64)
  unsigned short* mlp1 = (unsigned short*)(ws + 16 * MB);   // [16,48) after qkv dead
  unsigned short* Vt = (unsigned short*)(ws + 64 * MB);     // [64,80)
  unsigned short* h1 = (unsigned short*)(ws + 48 * MB);     // [48,80) after Vt dead
  unsigned short* t2 = (unsigned short*)(ws + 80 * MB);     // [80,96)
  unsigned short* Wqkvt = (unsigned short*)(ws + 96 * MB);  // [96,102)
  unsigned short* W1t = (unsigned short*)(ws + 102 * MB);   // [102,106)
  unsigned short* W2t = (unsigned short*)(ws + 106 * MB);   // [106,110)
  float* biasq = (float*)(ws + 110 * MB);

  // weight prep (tiled transposes, coalesced both sides)
  k_tr<<<dim3(2, 32, 16), 256, 0, stream>>>(Wq, Wqkvt, 64, 1024, 65536, 65536);
  k_tr<<<dim3(2, 32, 16), 256, 0, stream>>>(Wk, Wqkvt + 1048576, 64, 1024, 65536, 65536);
  k_tr<<<dim3(2, 32, 16), 256, 0, stream>>>(Wv, Wqkvt + 2097152, 64, 1024, 65536, 65536);
  k_tr<<<dim3(64, 32, 1), 256, 0, stream>>>(W1, W1t, 2048, 1024, 0, 0);
  k_tr<<<dim3(32, 64, 1), 256, 0, stream>>>(W2, W2t, 1024, 2048, 0, 0);
  k_bias3<<<12, 256, 0, stream>>>(bq, bk, bv, biasq);

  // pre-LN
  k_pre_ln<<<8192, 256, 0, stream>>>(X, pre_g, pre_b, t_bf);
  // QKV projection (V columns written transposed into Vt): 1536 blocks
  k_gemm3<<<dim3(24, 64), 256, 0, stream>>>(t_bf, Wqkvt, biasq, qkv, 8192, 3072, 1024, 2048, Vt);
  // attention
  k_attn4<<<2048, 256, 0, stream>>>(qkv, Vt, attn_o);
  // residual + post-LN (X1 stored in d_out)
  k_res_ln<<<8192, 256, 0, stream>>>(X, attn_o, post_g, post_b, out, t2);
  // MLP1: 1024 blocks
  k_gemm3<<<dim3(16, 64), 256, 0, stream>>>(t2, W1t, b1, mlp1, 8192, 2048, 1024, 1 << 30, nullptr);
  k_ln_gelu<<<8192, 256, 0, stream>>>(mlp1, ln1_g, ln1_b, h1);
  // MLP2: 512 blocks
  k_gemm3<<<dim3(8, 64), 256, 0, stream>>>(h1, W2t, b2, mlp2, 8192, 1024, 2048, 1 << 30, nullptr);
  // final: out = X1 + gelu(LN(mlp2))
  k_final<<<8192, 256, 0, stream>>>(mlp2, ln2_g, ln2_b, out);
}